// Round 5
// baseline (1219.669 us; speedup 1.0000x reference)
//
#include <hip/hip_runtime.h>
#include <hip/hip_bf16.h>

#define B_ 64
#define N_ 4096
#define C_ 256
#define K_ 8
#define M_ (B_*N_)
#define ITERS_ 3
#define SCALE_ 0.0625f
#define EPS_ 1e-8f

typedef __attribute__((ext_vector_type(4))) float f32x4;
typedef __attribute__((ext_vector_type(8))) unsigned short ushort8;

__device__ __forceinline__ unsigned short f2bf(float f){
    union { float f; unsigned u; } v; v.f = f;
    unsigned r = v.u + 0x7fffu + ((v.u >> 16) & 1u);
    return (unsigned short)(r >> 16);
}
__device__ __forceinline__ float bf2f(unsigned short h){
    union { unsigned u; float f; } v; v.u = ((unsigned)h) << 16;
    return v.f;
}

// ---------------- prep: slots init + WkT transpose ----------------
__global__ void prep_kernel(const float* __restrict__ mu, const float* __restrict__ lsig,
                            const float* __restrict__ noise, const float* __restrict__ Wk,
                            float* __restrict__ slots, float* __restrict__ WkT){
    int idx = blockIdx.x * 256 + threadIdx.x;   // 0..131071
    int c = idx & 255, i = (idx >> 8) & 7;
    slots[idx] = mu[c] + expf(lsig[c]) * noise[i*256 + c];
    if (idx < 65536){
        int cc = idx >> 8, d = idx & 255;       // WkT[cc][d] = Wk[d][cc]
        WkT[idx] = Wk[(size_t)d*256 + cc];
    }
}

// ---------------- x -> x_hat bf16; layout XH[jt][og(0..7)][rloc(0..255)][32c] ----------------
// Thread owns c in [sl*32, sl*32+32) -> og = sl; stores one contiguous 64B chunk.
__global__ __launch_bounds__(256)
void ln_kernel(const float* __restrict__ x, const float* __restrict__ g,
               const float* __restrict__ bta, unsigned short* __restrict__ XH){
    const int t = threadIdx.x;
    const int row = blockIdx.x*32 + (t >> 3), sl = t & 7;
    const float* xr = x + (size_t)row*C_ + sl*32;
    float v[32];
    #pragma unroll
    for (int q = 0; q < 8; ++q) *(float4*)&v[q*4] = *(const float4*)(xr + q*4);
    float sum = 0.f, sq = 0.f;
    #pragma unroll
    for (int e = 0; e < 32; ++e){ sum += v[e]; sq += v[e]*v[e]; }
    #pragma unroll
    for (int m = 1; m < 8; m <<= 1){ sum += __shfl_xor(sum, m); sq += __shfl_xor(sq, m); }
    float mean = sum * (1.f/256.f);
    float rstd = rsqrtf(sq * (1.f/256.f) - mean*mean + 1e-5f);
    const int jt = row >> 8, rloc = row & 255;
    unsigned short* dst = XH + (((size_t)jt*8 + sl)*256 + rloc)*32;
    #pragma unroll
    for (int u = 0; u < 4; ++u){
        float4 g0 = *(const float4*)(g + sl*32 + u*8);
        float4 g1 = *(const float4*)(g + sl*32 + u*8 + 4);
        float4 b0 = *(const float4*)(bta + sl*32 + u*8);
        float4 b1 = *(const float4*)(bta + sl*32 + u*8 + 4);
        const float* gp0 = (const float*)&g0; const float* gp1 = (const float*)&g1;
        const float* bp0 = (const float*)&b0; const float* bp1 = (const float*)&b1;
        ushort8 pk;
        #pragma unroll
        for (int e = 0; e < 4; ++e){
            pk[e]   = f2bf((v[u*8+e]   - mean)*rstd*gp0[e] + bp0[e]);
            pk[4+e] = f2bf((v[u*8+4+e] - mean)*rstd*gp1[e] + bp1[e]);
        }
        *(ushort8*)(dst + u*8) = pk;
    }
}

// ---------------- per-iter: slotq1 = LN_s(slots) -> q cols slice  (grid (B,4), 512 thr) ----------------
__global__ void slotq1_kernel(const float* __restrict__ slots, const float* __restrict__ Wq,
                              const float* __restrict__ bq, const float* __restrict__ gs,
                              const float* __restrict__ bs, float* __restrict__ qout){
    __shared__ float sn[8][260];
    const int t = threadIdx.x, b = blockIdx.x, cg = blockIdx.y;
    const int i = t >> 6, l = t & 63;
    {
        float4 v4 = *(const float4*)(slots + ((size_t)b*K_ + i)*C_ + l*4);
        float sum = v4.x + v4.y + v4.z + v4.w;
        float sq  = v4.x*v4.x + v4.y*v4.y + v4.z*v4.z + v4.w*v4.w;
        #pragma unroll
        for (int m = 1; m < 64; m <<= 1){ sum += __shfl_xor(sum, m); sq += __shfl_xor(sq, m); }
        float mean = sum * (1.f/256.f);
        float rstd = rsqrtf(sq * (1.f/256.f) - mean*mean + 1e-5f);
        float4 g4 = *(const float4*)(gs + l*4);
        float4 b4 = *(const float4*)(bs + l*4);
        sn[i][l*4+0] = (v4.x - mean)*rstd*g4.x + b4.x;
        sn[i][l*4+1] = (v4.y - mean)*rstd*g4.y + b4.y;
        sn[i][l*4+2] = (v4.z - mean)*rstd*g4.z + b4.z;
        sn[i][l*4+3] = (v4.w - mean)*rstd*g4.w + b4.w;
    }
    __syncthreads();
    const int col = cg*64 + l;
    float acc = bq[col];
    #pragma unroll 4
    for (int c = 0; c < 256; ++c)
        acc += sn[i][c] * Wq[(size_t)c*256 + col];
    qout[((size_t)b*K_ + i)*C_ + col] = acc;
}

// ---------------- per-iter: slotq2 = q~ slice + qb  (grid (B,4), 512 thr) ----------------
__global__ void slotq2_kernel(const float* __restrict__ qv, const float* __restrict__ WkT,
                              const float* __restrict__ bk, float* __restrict__ qtb,
                              float* __restrict__ qbb){
    __shared__ float qs[8][260];
    const int t = threadIdx.x, b = blockIdx.x, cg = blockIdx.y;
    const int i = t >> 6, l = t & 63;
    {
        float4 q4 = *(const float4*)(qv + ((size_t)b*K_ + i)*C_ + l*4);
        *(float4*)&qs[i][l*4] = q4;
        float4 k4 = *(const float4*)(bk + l*4);
        float pb = q4.x*k4.x + q4.y*k4.y + q4.z*k4.z + q4.w*k4.w;
        #pragma unroll
        for (int m = 1; m < 64; m <<= 1) pb += __shfl_xor(pb, m);
        if (cg == 0 && l == 0) qbb[(size_t)b*K_ + i] = pb * SCALE_;
    }
    __syncthreads();
    const int col = cg*64 + l;
    float acc = 0.f;
    #pragma unroll 4
    for (int c = 0; c < 256; ++c)
        acc += qs[i][c] * WkT[(size_t)c*256 + col];
    qtb[((size_t)b*K_ + i)*C_ + col] = acc * SCALE_;
}

// ---------------- per-iter: attn over x_hat basis (grid (B,16), 256 j per block) ----------------
__global__ __launch_bounds__(256, 4)
void attn_kernel(const unsigned short* __restrict__ XH, const float* __restrict__ qt,
                 const float* __restrict__ qb, float* __restrict__ Spart,
                 float* __restrict__ Upart){
    __shared__ float qts[8][264];
    __shared__ __align__(16) unsigned short ps[256*8];     // p bf16
    __shared__ __align__(16) unsigned short vbuf[32*256];  // swizzled x_hat chunk
    __shared__ float swred[4][9];
    const int t = threadIdx.x, b = blockIdx.x, jb = blockIdx.y;
    const unsigned short* XB = XH + (size_t)(b*16 + jb) * 65536;
    {
        const int i = t >> 5, c0 = (t & 31) * 8;
        const float* qp = qt + ((size_t)b*K_ + i)*C_ + c0;
        *(float4*)&qts[i][c0]     = *(const float4*)qp;
        *(float4*)&qts[i][c0 + 4] = *(const float4*)(qp + 4);
        if ((t & 31) == 0) qts[i][256] = qb[(size_t)b*K_ + i];
    }
    __syncthreads();
    // ---- QK: thread t owns j = t; layout [og][row][32c] ----
    float d[8];
    #pragma unroll
    for (int i = 0; i < 8; ++i) d[i] = qts[i][256];
    for (int og = 0; og < 8; ++og){
        const unsigned short* px = XB + ((size_t)og*256 + t)*32;
        ushort8 x0 = *(const ushort8*)(px);
        ushort8 x1 = *(const ushort8*)(px + 8);
        ushort8 x2 = *(const ushort8*)(px + 16);
        ushort8 x3 = *(const ushort8*)(px + 24);
        float xf[32];
        #pragma unroll
        for (int e = 0; e < 8; ++e){
            xf[e]    = bf2f(x0[e]);
            xf[8+e]  = bf2f(x1[e]);
            xf[16+e] = bf2f(x2[e]);
            xf[24+e] = bf2f(x3[e]);
        }
        #pragma unroll
        for (int i = 0; i < 8; ++i){
            float a = 0.f;
            #pragma unroll
            for (int q = 0; q < 8; ++q){
                const float4 q4 = *(const float4*)&qts[i][og*32 + q*4];
                a += q4.x*xf[q*4+0] + q4.y*xf[q*4+1] + q4.z*xf[q*4+2] + q4.w*xf[q*4+3];
            }
            d[i] += a;
        }
    }
    // ---- thread-local softmax over 8 slots (+EPS) ----
    float mx = d[0];
    #pragma unroll
    for (int i = 1; i < 8; ++i) mx = fmaxf(mx, d[i]);
    float e8[8], se = 0.f;
    #pragma unroll
    for (int i = 0; i < 8; ++i){ e8[i] = __expf(d[i] - mx); se += e8[i]; }
    float inv = 1.f / se;
    float p[8];
    #pragma unroll
    for (int i = 0; i < 8; ++i) p[i] = e8[i]*inv + EPS_;
    {
        ushort8 pp;
        #pragma unroll
        for (int i = 0; i < 8; ++i) pp[i] = f2bf(p[i]);
        *(ushort8*)&ps[t*8] = pp;
    }
    #pragma unroll
    for (int i = 0; i < 8; ++i){
        float s = p[i];
        #pragma unroll
        for (int m = 1; m < 64; m <<= 1) s += __shfl_xor(s, m);
        if ((t & 63) == 0) swred[t >> 6][i] = s;
    }
    __syncthreads();
    if (t < 8)
        Spart[((size_t)b*16 + jb)*8 + t] = swred[0][t] + swred[1][t] + swred[2][t] + swred[3][t];
    // ---- PV: u[islot][cg*8..+8) over all 256 j; chunks reversed for L2 reuse ----
    const int islot = t >> 5, cg = t & 31;
    const int r = t >> 3, sl = t & 7;
    f32x4 u0 = (f32x4){0.f,0.f,0.f,0.f}, u1 = (f32x4){0.f,0.f,0.f,0.f};
    for (int chx = 0; chx < 8; ++chx){
        const int ch = 7 - chx;
        #pragma unroll
        for (int uu = 0; uu < 4; ++uu){
            int o = sl*4 + uu;
            ushort8 xv = *(const ushort8*)(XB + (((size_t)sl*256) + ch*32 + r)*32 + uu*8);
            int phys = (o & 24) | ((o & 7) ^ (r & 7));
            *(ushort8*)&vbuf[r*256 + phys*8] = xv;
        }
        __syncthreads();
        #pragma unroll 4
        for (int jj = 0; jj < 32; ++jj){
            float pw = bf2f(ps[(ch*32 + jj)*8 + islot]);
            int pc = (cg & 24) | ((cg & 7) ^ (jj & 7));
            ushort8 vv = *(const ushort8*)&vbuf[jj*256 + pc*8];
            u0[0] += pw * bf2f(vv[0]); u0[1] += pw * bf2f(vv[1]);
            u0[2] += pw * bf2f(vv[2]); u0[3] += pw * bf2f(vv[3]);
            u1[0] += pw * bf2f(vv[4]); u1[1] += pw * bf2f(vv[5]);
            u1[2] += pw * bf2f(vv[6]); u1[3] += pw * bf2f(vv[7]);
        }
        __syncthreads();
    }
    {
        float* up = Upart + (((size_t)(b*16 + jb))*8 + islot)*C_ + cg*8;
        float4 o0; o0.x = u0[0]; o0.y = u0[1]; o0.z = u0[2]; o0.w = u0[3];
        float4 o1; o1.x = u1[0]; o1.y = u1[1]; o1.z = u1[2]; o1.w = u1[3];
        *(float4*)up       = o0;
        *(float4*)(up + 4) = o1;
    }
}

// ---------------- per-iter: slotu1 = reduce + Wv-GEMM + GRU cols slice  (grid (B,4), 512 thr) ----------------
__global__ void slotu1_kernel(const float* __restrict__ slots, const float* __restrict__ Spart,
                              const float* __restrict__ Upart, const float* __restrict__ Wv,
                              const float* __restrict__ bv, const float* __restrict__ W_ih,
                              const float* __restrict__ b_ih, const float* __restrict__ W_hh,
                              const float* __restrict__ b_hh, float* __restrict__ slots2){
    __shared__ float us[8][260], sp[8][260], upd[8][260];
    const int t = threadIdx.x, b = blockIdx.x, cg = blockIdx.y;
    const int i = t >> 6, l = t & 63;
    {
        float a0 = 0.f, a1 = 0.f, a2 = 0.f, a3 = 0.f, S = 0.f;
        for (int jb = 0; jb < 16; ++jb){
            float4 u4 = *(const float4*)(Upart + (((size_t)(b*16 + jb))*8 + i)*C_ + l*4);
            a0 += u4.x; a1 += u4.y; a2 += u4.z; a3 += u4.w;
            S += Spart[((size_t)b*16 + jb)*8 + i];
        }
        float invS = 1.f / S;
        us[i][l*4+0] = a0*invS; us[i][l*4+1] = a1*invS;
        us[i][l*4+2] = a2*invS; us[i][l*4+3] = a3*invS;
        float4 s4 = *(const float4*)(slots + ((size_t)b*K_ + i)*C_ + l*4);
        sp[i][l*4+0] = s4.x; sp[i][l*4+1] = s4.y; sp[i][l*4+2] = s4.z; sp[i][l*4+3] = s4.w;
    }
    __syncthreads();
    {   // updates = us @ Wv + bv  (full 256 cols; 4 slots per thread)
        const int col = t & 255, ig = t >> 8;
        float ac0 = bv[col], ac1 = ac0, ac2 = ac0, ac3 = ac0;
        #pragma unroll 2
        for (int c = 0; c < 256; ++c){
            float w = Wv[(size_t)c*256 + col];
            ac0 += us[ig*4+0][c]*w; ac1 += us[ig*4+1][c]*w;
            ac2 += us[ig*4+2][c]*w; ac3 += us[ig*4+3][c]*w;
        }
        upd[ig*4+0][col] = ac0; upd[ig*4+1][col] = ac1;
        upd[ig*4+2][col] = ac2; upd[ig*4+3][col] = ac3;
    }
    __syncthreads();
    {   // GRU, cols slice [cg*64, +64)
        const int n = cg*64 + l;
        float xr = b_ih[n], xz = b_ih[256+n], xn = b_ih[512+n];
        float hr = b_hh[n], hz = b_hh[256+n], hn = b_hh[512+n];
        #pragma unroll 2
        for (int c = 0; c < 256; ++c){
            float uv = upd[i][c], sv = sp[i][c];
            const float* wi = W_ih + (size_t)c * 768 + n;
            const float* wh = W_hh + (size_t)c * 768 + n;
            xr += uv*wi[0];   xz += uv*wi[256]; xn += uv*wi[512];
            hr += sv*wh[0];   hz += sv*wh[256]; hn += sv*wh[512];
        }
        float rv = 1.f/(1.f + __expf(-(xr + hr)));
        float zv = 1.f/(1.f + __expf(-(xz + hz)));
        float nn = tanhf(xn + rv*hn);
        float o  = (1.f - zv)*nn + zv*sp[i][n];
        slots2[((size_t)b*K_ + i)*C_ + n] = o;
    }
}

// ---------------- per-iter: slotu2 = LN_ff + FFN1 + FFN2 cols slice  (grid (B,4), 512 thr) ----------------
__global__ void slotu2_kernel(const float* __restrict__ slots2, const float* __restrict__ gf,
                              const float* __restrict__ bf, const float* __restrict__ W1,
                              const float* __restrict__ b1, const float* __restrict__ W2,
                              const float* __restrict__ b2, float* __restrict__ slots,
                              float* __restrict__ dout){
    __shared__ float s0[8][260], pre[8][260], hb[8][260];
    const int t = threadIdx.x, b = blockIdx.x, cg = blockIdx.y;
    const int i = t >> 6, l = t & 63;
    {
        float4 v4 = *(const float4*)(slots2 + ((size_t)b*K_ + i)*C_ + l*4);
        float sum = v4.x + v4.y + v4.z + v4.w;
        float sq  = v4.x*v4.x + v4.y*v4.y + v4.z*v4.z + v4.w*v4.w;
        #pragma unroll
        for (int m = 1; m < 64; m <<= 1){ sum += __shfl_xor(sum, m); sq += __shfl_xor(sq, m); }
        float mean = sum * (1.f/256.f);
        float rstd = rsqrtf(sq * (1.f/256.f) - mean*mean + 1e-5f);
        float4 g4 = *(const float4*)(gf + l*4);
        float4 b4 = *(const float4*)(bf + l*4);
        s0[i][l*4+0] = v4.x; s0[i][l*4+1] = v4.y; s0[i][l*4+2] = v4.z; s0[i][l*4+3] = v4.w;
        pre[i][l*4+0] = (v4.x - mean)*rstd*g4.x + b4.x;
        pre[i][l*4+1] = (v4.y - mean)*rstd*g4.y + b4.y;
        pre[i][l*4+2] = (v4.z - mean)*rstd*g4.z + b4.z;
        pre[i][l*4+3] = (v4.w - mean)*rstd*g4.w + b4.w;
    }
    __syncthreads();
    {   // h = relu(pre @ W1 + b1)  (full 256 cols; 4 slots per thread)
        const int col = t & 255, ig = t >> 8;
        float ac0 = b1[col], ac1 = ac0, ac2 = ac0, ac3 = ac0;
        #pragma unroll 2
        for (int c = 0; c < 256; ++c){
            float w = W1[(size_t)c*256 + col];
            ac0 += pre[ig*4+0][c]*w; ac1 += pre[ig*4+1][c]*w;
            ac2 += pre[ig*4+2][c]*w; ac3 += pre[ig*4+3][c]*w;
        }
        hb[ig*4+0][col] = fmaxf(ac0, 0.f); hb[ig*4+1][col] = fmaxf(ac1, 0.f);
        hb[ig*4+2][col] = fmaxf(ac2, 0.f); hb[ig*4+3][col] = fmaxf(ac3, 0.f);
    }
    __syncthreads();
    {   // out = s0 + h @ W2 + b2, cols slice
        const int n = cg*64 + l;
        float acc = b2[n];
        #pragma unroll 4
        for (int m = 0; m < 256; ++m)
            acc += hb[i][m] * W2[(size_t)m*256 + n];
        float val = s0[i][n] + acc;
        size_t off = ((size_t)b*K_ + i)*C_ + n;
        slots[off] = val;
        dout[off]  = val;
    }
}

extern "C" void kernel_launch(void* const* d_in, const int* in_sizes, int n_in,
                              void* d_out, int out_size, void* d_ws, size_t ws_size,
                              hipStream_t stream){
    const float* inputs = (const float*)d_in[0];
    const float* noise  = (const float*)d_in[1];
    const float* mu     = (const float*)d_in[2];
    const float* lsig   = (const float*)d_in[3];
    const float* g_in   = (const float*)d_in[4];
    const float* b_in   = (const float*)d_in[5];
    const float* g_s    = (const float*)d_in[6];
    const float* b_s    = (const float*)d_in[7];
    const float* g_ff   = (const float*)d_in[8];
    const float* b_ff   = (const float*)d_in[9];
    const float* Wq     = (const float*)d_in[10];
    const float* bq     = (const float*)d_in[11];
    const float* Wk     = (const float*)d_in[12];
    const float* bk     = (const float*)d_in[13];
    const float* Wv     = (const float*)d_in[14];
    const float* bv     = (const float*)d_in[15];
    const float* W_ih   = (const float*)d_in[16];
    const float* b_ih   = (const float*)d_in[17];
    const float* W_hh   = (const float*)d_in[18];
    const float* b_hh   = (const float*)d_in[19];
    const float* W1     = (const float*)d_in[20];
    const float* b1     = (const float*)d_in[21];
    const float* W2     = (const float*)d_in[22];
    const float* b2     = (const float*)d_in[23];

    char* ws = (char*)d_ws;
    unsigned short* XH  = (unsigned short*)(ws);               // 128 MB
    float* Upart        = (float*)(ws + ((size_t)128 << 20));  // 8 MB
    float* Spart        = (float*)(ws + ((size_t)136 << 20));  // 8 KB
    float* qbuf         = (float*)(ws + ((size_t)137 << 20));  // 512 KB
    float* qtbuf        = (float*)(ws + ((size_t)138 << 20));  // 512 KB
    float* qbbuf        = (float*)(ws + ((size_t)139 << 20));  // 2 KB
    float* slots        = (float*)(ws + ((size_t)140 << 20));  // 512 KB
    float* slots2       = (float*)(ws + ((size_t)141 << 20));  // 512 KB
    float* WkT          = (float*)(ws + ((size_t)142 << 20));  // 256 KB

    prep_kernel<<<512, 256, 0, stream>>>(mu, lsig, noise, Wk, slots, WkT);
    ln_kernel<<<M_/32, 256, 0, stream>>>(inputs, g_in, b_in, XH);
    for (int it = 0; it < ITERS_; ++it){
        slotq1_kernel<<<dim3(B_, 4), 512, 0, stream>>>(slots, Wq, bq, g_s, b_s, qbuf);
        slotq2_kernel<<<dim3(B_, 4), 512, 0, stream>>>(qbuf, WkT, bk, qtbuf, qbbuf);
        attn_kernel<<<dim3(B_, 16), 256, 0, stream>>>(XH, qtbuf, qbbuf, Spart, Upart);
        slotu1_kernel<<<dim3(B_, 4), 512, 0, stream>>>(slots, Spart, Upart, Wv, bv,
                                                       W_ih, b_ih, W_hh, b_hh, slots2);
        slotu2_kernel<<<dim3(B_, 4), 512, 0, stream>>>(slots2, g_ff, b_ff, W1, b1, W2, b2,
                                                       slots, (float*)d_out);
    }
}

// Round 6
// 748.861 us; speedup vs baseline: 1.6287x; 1.6287x over previous
//
#include <hip/hip_runtime.h>
#include <hip/hip_bf16.h>

#define B_ 64
#define N_ 4096
#define C_ 256
#define K_ 8
#define M_ (B_*N_)
#define ITERS_ 3
#define SCALE_ 0.0625f
#define EPS_ 1e-8f

typedef __attribute__((ext_vector_type(4))) float f32x4;
typedef __attribute__((ext_vector_type(8))) unsigned short ushort8;

static __device__ __forceinline__ unsigned short f2bf(float f){
    union { float f; unsigned u; } v; v.f = f;
    unsigned r = v.u + 0x7fffu + ((v.u >> 16) & 1u);
    return (unsigned short)(r >> 16);
}
static __device__ __forceinline__ float bf2f(unsigned short h){
    union { unsigned u; float f; } v; v.u = ((unsigned)h) << 16;
    return v.f;
}

// ---------------- prep1: slots init ----------------
__global__ void prep1_kernel(const float* __restrict__ mu, const float* __restrict__ lsig,
                             const float* __restrict__ noise, float* __restrict__ slots){
    int idx = blockIdx.x*256 + threadIdx.x;   // 0..131071
    int c = idx & 255, i = (idx >> 8) & 7;
    slots[idx] = mu[c] + expf(lsig[c])*noise[i*256 + c];
}

// ---------------- prep2: WqkT = Wq@Wk^T, bqt = bq@Wk^T, wqb = Wq@bk, bqk = bq.bk ----------------
__global__ void prep2_kernel(const float* __restrict__ Wq, const float* __restrict__ Wk,
                             const float* __restrict__ bq, const float* __restrict__ bk,
                             float* __restrict__ WqkT, float* __restrict__ bqt,
                             float* __restrict__ wqb, float* __restrict__ bqkv){
    __shared__ float wqrow[256], bkl[256], bql[256];
    __shared__ float red[4], red2[4];
    const int t = threadIdx.x, c = blockIdx.x;
    wqrow[t] = Wq[(size_t)c*256 + t];
    bkl[t] = bk[t];
    bql[t] = bq[t];
    __syncthreads();
    float acc = 0.f, accb = 0.f;
    const float* wkr = Wk + (size_t)t*256;
    #pragma unroll 4
    for (int d = 0; d < 256; d += 4){
        float4 wk4 = *(const float4*)(wkr + d);
        float4 wq4 = *(const float4*)(&wqrow[d]);
        float4 bq4 = *(const float4*)(&bql[d]);
        acc  += wq4.x*wk4.x + wq4.y*wk4.y + wq4.z*wk4.z + wq4.w*wk4.w;
        accb += bq4.x*wk4.x + bq4.y*wk4.y + bq4.z*wk4.z + bq4.w*wk4.w;
    }
    WqkT[(size_t)c*256 + t] = acc;
    if (c == 0) bqt[t] = accb;
    float pw = wqrow[t]*bkl[t];
    float pb = bql[t]*bkl[t];
    #pragma unroll
    for (int m = 1; m < 64; m <<= 1){ pw += __shfl_xor(pw, m); pb += __shfl_xor(pb, m); }
    if ((t & 63) == 0){ red[t >> 6] = pw; red2[t >> 6] = pb; }
    __syncthreads();
    if (t == 0){
        wqb[c] = red[0] + red[1] + red[2] + red[3];
        if (c == 0) bqkv[0] = red2[0] + red2[1] + red2[2] + red2[3];
    }
}

// ---------------- x -> x_hat bf16; layout XH[jt][og(0..7)][rloc(0..255)][32c] ----------------
__global__ void ln_kernel(const float* __restrict__ x, const float* __restrict__ g,
                          const float* __restrict__ bta, unsigned short* __restrict__ XH){
    const int t = threadIdx.x;
    const int row = blockIdx.x*32 + (t >> 3), sl = t & 7;
    const float* xr = x + (size_t)row*C_ + sl*32;
    float v[32];
    #pragma unroll
    for (int q = 0; q < 8; ++q) *(float4*)&v[q*4] = *(const float4*)(xr + q*4);
    float sum = 0.f, sq = 0.f;
    #pragma unroll
    for (int e = 0; e < 32; ++e){ sum += v[e]; sq += v[e]*v[e]; }
    #pragma unroll
    for (int m = 1; m < 8; m <<= 1){ sum += __shfl_xor(sum, m); sq += __shfl_xor(sq, m); }
    float mean = sum * (1.f/256.f);
    float rstd = rsqrtf(sq * (1.f/256.f) - mean*mean + 1e-5f);
    const int jt = row >> 8, rloc = row & 255;
    unsigned short* dst = XH + (((size_t)jt*8 + sl)*256 + rloc)*32;
    #pragma unroll
    for (int u = 0; u < 4; ++u){
        float4 g0 = *(const float4*)(g + sl*32 + u*8);
        float4 g1 = *(const float4*)(g + sl*32 + u*8 + 4);
        float4 b0 = *(const float4*)(bta + sl*32 + u*8);
        float4 b1 = *(const float4*)(bta + sl*32 + u*8 + 4);
        const float* gp0 = (const float*)&g0; const float* gp1 = (const float*)&g1;
        const float* bp0 = (const float*)&b0; const float* bp1 = (const float*)&b1;
        ushort8 pk;
        #pragma unroll
        for (int e = 0; e < 4; ++e){
            pk[e]   = f2bf((v[u*8+e]   - mean)*rstd*gp0[e] + bp0[e]);
            pk[4+e] = f2bf((v[u*8+4+e] - mean)*rstd*gp1[e] + bp1[e]);
        }
        *(ushort8*)(dst + u*8) = pk;
    }
}

// ---------------- per-iter: slotq = LN_s + q~ = SCALE*(sn@Wqk + bqt), qb  (grid (B,4), 512) ----------------
__global__ void slotq_kernel(const float* __restrict__ slots, const float* __restrict__ WqkT,
                             const float* __restrict__ bqt, const float* __restrict__ wqb,
                             const float* __restrict__ bqkv, const float* __restrict__ gs,
                             const float* __restrict__ bs, float* __restrict__ qtbuf,
                             float* __restrict__ qbb){
    __shared__ float sn[8][260];
    const int t = threadIdx.x, b = blockIdx.x, cgb = blockIdx.y;
    const int i = t >> 6, l = t & 63;
    {
        float4 v4 = *(const float4*)(slots + ((size_t)b*8 + i)*256 + l*4);
        float sum = v4.x + v4.y + v4.z + v4.w;
        float sq  = v4.x*v4.x + v4.y*v4.y + v4.z*v4.z + v4.w*v4.w;
        #pragma unroll
        for (int m = 1; m < 64; m <<= 1){ sum += __shfl_xor(sum, m); sq += __shfl_xor(sq, m); }
        float mean = sum * (1.f/256.f);
        float rstd = rsqrtf(sq * (1.f/256.f) - mean*mean + 1e-5f);
        float4 g4 = *(const float4*)(gs + l*4);
        float4 b4 = *(const float4*)(bs + l*4);
        float n0 = (v4.x - mean)*rstd*g4.x + b4.x;
        float n1 = (v4.y - mean)*rstd*g4.y + b4.y;
        float n2 = (v4.z - mean)*rstd*g4.z + b4.z;
        float n3 = (v4.w - mean)*rstd*g4.w + b4.w;
        sn[i][l*4+0] = n0; sn[i][l*4+1] = n1; sn[i][l*4+2] = n2; sn[i][l*4+3] = n3;
        if (cgb == 0){
            float4 w4 = *(const float4*)(wqb + l*4);
            float pb = n0*w4.x + n1*w4.y + n2*w4.z + n3*w4.w;
            #pragma unroll
            for (int m = 1; m < 64; m <<= 1) pb += __shfl_xor(pb, m);
            if (l == 0) qbb[(size_t)b*8 + i] = SCALE_*(pb + bqkv[0]);
        }
    }
    __syncthreads();
    const int col = cgb*64 + l;
    float acc = bqt[col];
    #pragma unroll 8
    for (int c = 0; c < 256; ++c)
        acc += sn[i][c] * WqkT[(size_t)c*256 + col];
    qtbuf[((size_t)b*8 + i)*256 + col] = SCALE_*acc;
}

// ---------------- per-iter: fused attn (QK + softmax + PV, single x_hat pass)  (grid (B,16), 256) ----------------
__global__ void attn_kernel(const unsigned short* __restrict__ XH, const float* __restrict__ qt,
                            const float* __restrict__ qb, float* __restrict__ Spart,
                            float* __restrict__ Upart){
    __shared__ __align__(16) unsigned short xs[2*8192];   // 2 x 32rows x 256c, swizzled
    __shared__ __align__(16) float qts2[8*292 + 4];       // q~ padded: [cs]*292 + i*36 + e
    __shared__ float qbs[8];
    __shared__ __align__(16) unsigned short ps[32*8];     // p bf16 for current chunk [j][i]
    __shared__ float swred[4][8];
    const int t = threadIdx.x, b = blockIdx.x, jb = blockIdx.y;
    const unsigned short* XB = XH + (size_t)(b*16 + jb)*65536;
    {
        const int i = t >> 5, c0 = (t & 31)*8;
        const float* qp = qt + ((size_t)b*8 + i)*256 + c0;
        float4 a0 = *(const float4*)qp;
        float4 a1 = *(const float4*)(qp + 4);
        float* dst = &qts2[(c0 >> 5)*292 + i*36 + (c0 & 31)];
        *(float4*)dst = a0;
        *(float4*)(dst + 4) = a1;
        if ((t & 31) == 0) qbs[i] = qb[(size_t)b*8 + i];
    }
    const int og = t >> 5, r = t & 31;
    const int ssw = (r & 7) << 3;
    ushort8 s0, s1, s2, s3;
    {
        const unsigned short* g0 = XB + ((size_t)og*256 + r)*32;
        s0 = *(const ushort8*)(g0);      s1 = *(const ushort8*)(g0 + 8);
        s2 = *(const ushort8*)(g0 + 16); s3 = *(const ushort8*)(g0 + 24);
    }
    {
        unsigned short* xw = &xs[r*256];
        *(ushort8*)&xw[(og*32 +  0) ^ ssw] = s0;
        *(ushort8*)&xw[(og*32 +  8) ^ ssw] = s1;
        *(ushort8*)&xw[(og*32 + 16) ^ ssw] = s2;
        *(ushort8*)&xw[(og*32 + 24) ^ ssw] = s3;
    }
    __syncthreads();

    const int jl = t >> 3, cs = t & 7;
    const int jsw = (jl & 7) << 3;
    const int csb = cs*292;
    const int islot = t >> 5, cg = t & 31;
    f32x4 u0 = (f32x4){0.f,0.f,0.f,0.f}, u1 = (f32x4){0.f,0.f,0.f,0.f};
    float s8a[8] = {0.f,0.f,0.f,0.f,0.f,0.f,0.f,0.f};

    for (int ch = 0; ch < 8; ++ch){
        const int cur = (ch & 1) << 13;
        if (ch < 7){
            const unsigned short* g1 = XB + ((size_t)og*256 + (ch+1)*32 + r)*32;
            s0 = *(const ushort8*)(g1);      s1 = *(const ushort8*)(g1 + 8);
            s2 = *(const ushort8*)(g1 + 16); s3 = *(const ushort8*)(g1 + 24);
        }
        // ---- QK: thread (jl, cs) covers c in [cs*32, +32) of row jl ----
        float pd[8] = {0.f,0.f,0.f,0.f,0.f,0.f,0.f,0.f};
        const unsigned short* xrow = &xs[cur + jl*256];
        #pragma unroll
        for (int k = 0; k < 4; ++k){
            ushort8 xv = *(const ushort8*)&xrow[(cs*32 + k*8) ^ jsw];
            float xf0 = bf2f(xv[0]), xf1 = bf2f(xv[1]), xf2 = bf2f(xv[2]), xf3 = bf2f(xv[3]);
            float xf4 = bf2f(xv[4]), xf5 = bf2f(xv[5]), xf6 = bf2f(xv[6]), xf7 = bf2f(xv[7]);
            #pragma unroll
            for (int i = 0; i < 8; ++i){
                const float* qp2 = &qts2[csb + i*36 + k*8];
                float4 qa = *(const float4*)qp2;
                float4 qc = *(const float4*)(qp2 + 4);
                pd[i] += qa.x*xf0 + qa.y*xf1 + qa.z*xf2 + qa.w*xf3
                       + qc.x*xf4 + qc.y*xf5 + qc.z*xf6 + qc.w*xf7;
            }
        }
        float p[8];
        {
            float d8[8];
            #pragma unroll
            for (int i = 0; i < 8; ++i){
                float v = pd[i];
                v += __shfl_xor(v, 1);
                v += __shfl_xor(v, 2);
                v += __shfl_xor(v, 4);
                d8[i] = v + qbs[i];
            }
            float mx = d8[0];
            #pragma unroll
            for (int i = 1; i < 8; ++i) mx = fmaxf(mx, d8[i]);
            float se = 0.f;
            #pragma unroll
            for (int i = 0; i < 8; ++i){ p[i] = __expf(d8[i] - mx); se += p[i]; }
            float inv = 1.f / se;
            #pragma unroll
            for (int i = 0; i < 8; ++i){ p[i] = p[i]*inv + EPS_; s8a[i] += p[i]; }
        }
        if (cs == 0){
            ushort8 pp;
            #pragma unroll
            for (int i = 0; i < 8; ++i) pp[i] = f2bf(p[i]);
            *(ushort8*)&ps[jl*8] = pp;
        }
        if (ch < 7){
            unsigned short* xw = &xs[(cur ^ 8192) + r*256];
            *(ushort8*)&xw[(og*32 +  0) ^ ssw] = s0;
            *(ushort8*)&xw[(og*32 +  8) ^ ssw] = s1;
            *(ushort8*)&xw[(og*32 + 16) ^ ssw] = s2;
            *(ushort8*)&xw[(og*32 + 24) ^ ssw] = s3;
        }
        __syncthreads();
        // ---- PV: thread (islot, cg) accumulates u over this chunk's 32 rows ----
        #pragma unroll 4
        for (int jj = 0; jj < 32; ++jj){
            float pw = bf2f(ps[jj*8 + islot]);
            ushort8 vv = *(const ushort8*)&xs[cur + jj*256 + ((cg*8) ^ ((jj & 7) << 3))];
            u0[0] += pw*bf2f(vv[0]); u0[1] += pw*bf2f(vv[1]);
            u0[2] += pw*bf2f(vv[2]); u0[3] += pw*bf2f(vv[3]);
            u1[0] += pw*bf2f(vv[4]); u1[1] += pw*bf2f(vv[5]);
            u1[2] += pw*bf2f(vv[6]); u1[3] += pw*bf2f(vv[7]);
        }
        __syncthreads();
    }
    {
        #pragma unroll
        for (int i = 0; i < 8; ++i){
            float v = s8a[i];
            #pragma unroll
            for (int m = 1; m < 64; m <<= 1) v += __shfl_xor(v, m);
            if ((t & 63) == 0) swred[t >> 6][i] = v;
        }
        __syncthreads();
        if (t < 8)
            Spart[((size_t)(b*16 + jb))*8 + t] =
                (swred[0][t] + swred[1][t] + swred[2][t] + swred[3][t]) * 0.125f;
    }
    {
        float* up = Upart + (((size_t)(b*16 + jb))*8 + islot)*256 + cg*8;
        float4 o0; o0.x = u0[0]; o0.y = u0[1]; o0.z = u0[2]; o0.w = u0[3];
        float4 o1; o1.x = u1[0]; o1.y = u1[1]; o1.z = u1[2]; o1.w = u1[3];
        *(float4*)up       = o0;
        *(float4*)(up + 4) = o1;
    }
}

// ---------------- per-iter: slotu1 = Upart reduce + Wv GEMM + GRU n-slice  (grid (B,4), 512) ----------------
__global__ void slotu1_kernel(const float* __restrict__ slots, const float* __restrict__ Spart,
                              const float* __restrict__ Upart, const float* __restrict__ Wv,
                              const float* __restrict__ bv, const float* __restrict__ W_ih,
                              const float* __restrict__ b_ih, const float* __restrict__ W_hh,
                              const float* __restrict__ b_hh, float* __restrict__ slots2){
    __shared__ float us[8][260], sp[8][260], upd[8][260];
    const int t = threadIdx.x, b = blockIdx.x, ng = blockIdx.y;
    const int i = t >> 6, l = t & 63;
    {
        float a0 = 0.f, a1 = 0.f, a2 = 0.f, a3 = 0.f, S = 0.f;
        for (int jbl = 0; jbl < 16; ++jbl){
            float4 u4 = *(const float4*)(Upart + (((size_t)(b*16 + jbl))*8 + i)*256 + l*4);
            a0 += u4.x; a1 += u4.y; a2 += u4.z; a3 += u4.w;
            S += Spart[((size_t)(b*16 + jbl))*8 + i];
        }
        float invS = 1.f / S;
        us[i][l*4+0] = a0*invS; us[i][l*4+1] = a1*invS;
        us[i][l*4+2] = a2*invS; us[i][l*4+3] = a3*invS;
        float4 s4 = *(const float4*)(slots + ((size_t)b*8 + i)*256 + l*4);
        sp[i][l*4+0] = s4.x; sp[i][l*4+1] = s4.y; sp[i][l*4+2] = s4.z; sp[i][l*4+3] = s4.w;
    }
    __syncthreads();
    {   // upd = us @ Wv + bv (full width, redundant across ng blocks)
        const int c4 = l*4;
        float4 acc = *(const float4*)(bv + c4);
        #pragma unroll 4
        for (int c = 0; c < 256; ++c){
            float uv = us[i][c];
            float4 w4 = *(const float4*)(Wv + (size_t)c*256 + c4);
            acc.x += uv*w4.x; acc.y += uv*w4.y; acc.z += uv*w4.z; acc.w += uv*w4.w;
        }
        *(float4*)&upd[i][c4] = acc;
    }
    __syncthreads();
    {   // GRU for n-slice
        const int n = ng*64 + l;
        float xr = b_ih[n], xz = b_ih[256+n], xn = b_ih[512+n];
        float hr = b_hh[n], hz = b_hh[256+n], hn = b_hh[512+n];
        #pragma unroll 2
        for (int c = 0; c < 256; ++c){
            float uv = upd[i][c], sv = sp[i][c];
            const float* wi = W_ih + (size_t)c*768 + n;
            const float* wh = W_hh + (size_t)c*768 + n;
            xr += uv*wi[0];  xz += uv*wi[256]; xn += uv*wi[512];
            hr += sv*wh[0];  hz += sv*wh[256]; hn += sv*wh[512];
        }
        float rv = 1.f/(1.f + __expf(-(xr + hr)));
        float zv = 1.f/(1.f + __expf(-(xz + hz)));
        float nn = tanhf(xn + rv*hn);
        slots2[((size_t)b*8 + i)*256 + n] = (1.f - zv)*nn + zv*sp[i][n];
    }
}

// ---------------- per-iter: slotu2 = LN_ff + FFN1 + FFN2 n-slice  (grid (B,4), 512) ----------------
__global__ void slotu2_kernel(const float* __restrict__ slots2, const float* __restrict__ gf,
                              const float* __restrict__ bf, const float* __restrict__ W1,
                              const float* __restrict__ b1, const float* __restrict__ W2,
                              const float* __restrict__ b2, float* __restrict__ slots,
                              float* __restrict__ dout){
    __shared__ float s0[8][260], pre[8][260], hb[8][260];
    const int t = threadIdx.x, b = blockIdx.x, ng = blockIdx.y;
    const int i = t >> 6, l = t & 63;
    {
        float4 v4 = *(const float4*)(slots2 + ((size_t)b*8 + i)*256 + l*4);
        float sum = v4.x + v4.y + v4.z + v4.w;
        float sq  = v4.x*v4.x + v4.y*v4.y + v4.z*v4.z + v4.w*v4.w;
        #pragma unroll
        for (int m = 1; m < 64; m <<= 1){ sum += __shfl_xor(sum, m); sq += __shfl_xor(sq, m); }
        float mean = sum * (1.f/256.f);
        float rstd = rsqrtf(sq * (1.f/256.f) - mean*mean + 1e-5f);
        float4 g4 = *(const float4*)(gf + l*4);
        float4 b4 = *(const float4*)(bf + l*4);
        s0[i][l*4+0] = v4.x; s0[i][l*4+1] = v4.y; s0[i][l*4+2] = v4.z; s0[i][l*4+3] = v4.w;
        pre[i][l*4+0] = (v4.x - mean)*rstd*g4.x + b4.x;
        pre[i][l*4+1] = (v4.y - mean)*rstd*g4.y + b4.y;
        pre[i][l*4+2] = (v4.z - mean)*rstd*g4.z + b4.z;
        pre[i][l*4+3] = (v4.w - mean)*rstd*g4.w + b4.w;
    }
    __syncthreads();
    {   // h = relu(pre @ W1 + b1) (full width, redundant)
        const int h4 = l*4;
        float4 acc = *(const float4*)(b1 + h4);
        #pragma unroll 4
        for (int c = 0; c < 256; ++c){
            float pv = pre[i][c];
            float4 w4 = *(const float4*)(W1 + (size_t)c*256 + h4);
            acc.x += pv*w4.x; acc.y += pv*w4.y; acc.z += pv*w4.z; acc.w += pv*w4.w;
        }
        hb[i][h4+0] = fmaxf(acc.x, 0.f); hb[i][h4+1] = fmaxf(acc.y, 0.f);
        hb[i][h4+2] = fmaxf(acc.z, 0.f); hb[i][h4+3] = fmaxf(acc.w, 0.f);
    }
    __syncthreads();
    {   // out = s0 + h @ W2 + b2, n-slice
        const int n = ng*64 + l;
        float acc = b2[n];
        #pragma unroll 8
        for (int m = 0; m < 256; ++m)
            acc += hb[i][m] * W2[(size_t)m*256 + n];
        float val = s0[i][n] + acc;
        size_t off = ((size_t)b*8 + i)*256 + n;
        slots[off] = val;
        dout[off]  = val;
    }
}

extern "C" void kernel_launch(void* const* d_in, const int* in_sizes, int n_in,
                              void* d_out, int out_size, void* d_ws, size_t ws_size,
                              hipStream_t stream){
    const float* inputs = (const float*)d_in[0];
    const float* noise  = (const float*)d_in[1];
    const float* mu     = (const float*)d_in[2];
    const float* lsig   = (const float*)d_in[3];
    const float* g_in   = (const float*)d_in[4];
    const float* b_in   = (const float*)d_in[5];
    const float* g_s    = (const float*)d_in[6];
    const float* b_s    = (const float*)d_in[7];
    const float* g_ff   = (const float*)d_in[8];
    const float* b_ff   = (const float*)d_in[9];
    const float* Wq     = (const float*)d_in[10];
    const float* bq     = (const float*)d_in[11];
    const float* Wk     = (const float*)d_in[12];
    const float* bk     = (const float*)d_in[13];
    const float* Wv     = (const float*)d_in[14];
    const float* bv     = (const float*)d_in[15];
    const float* W_ih   = (const float*)d_in[16];
    const float* b_ih   = (const float*)d_in[17];
    const float* W_hh   = (const float*)d_in[18];
    const float* b_hh   = (const float*)d_in[19];
    const float* W1     = (const float*)d_in[20];
    const float* b1     = (const float*)d_in[21];
    const float* W2     = (const float*)d_in[22];
    const float* b2     = (const float*)d_in[23];

    char* ws = (char*)d_ws;
    unsigned short* XH  = (unsigned short*)(ws);               // 128 MB
    float* Upart        = (float*)(ws + ((size_t)128 << 20));  // 8 MB
    float* Spart        = (float*)(ws + ((size_t)136 << 20));  // 8 KB
    float* qtbuf        = (float*)(ws + ((size_t)137 << 20));  // 512 KB
    float* qbb          = (float*)(ws + ((size_t)138 << 20));  // 2 KB
    float* slots        = (float*)(ws + ((size_t)139 << 20));  // 512 KB
    float* slots2       = (float*)(ws + ((size_t)140 << 20));  // 512 KB
    float* WqkT         = (float*)(ws + ((size_t)141 << 20));  // 256 KB
    float* bqt          = (float*)(ws + ((size_t)142 << 20));  // 1 KB
    float* wqb          = (float*)(ws + ((size_t)143 << 20));  // 1 KB
    float* bqkv         = (float*)(ws + ((size_t)144 << 20));  // 4 B

    prep1_kernel<<<512, 256, 0, stream>>>(mu, lsig, noise, slots);
    prep2_kernel<<<256, 256, 0, stream>>>(Wq, Wk, bq, bk, WqkT, bqt, wqb, bqkv);
    ln_kernel<<<M_/32, 256, 0, stream>>>(inputs, g_in, b_in, XH);
    for (int it = 0; it < ITERS_; ++it){
        slotq_kernel<<<dim3(B_, 4), 512, 0, stream>>>(slots, WqkT, bqt, wqb, bqkv,
                                                      g_s, b_s, qtbuf, qbb);
        attn_kernel<<<dim3(B_, 16), 256, 0, stream>>>(XH, qtbuf, qbb, Spart, Upart);
        slotu1_kernel<<<dim3(B_, 4), 512, 0, stream>>>(slots, Spart, Upart, Wv, bv,
                                                       W_ih, b_ih, W_hh, b_hh, slots2);
        slotu2_kernel<<<dim3(B_, 4), 512, 0, stream>>>(slots2, g_ff, b_ff, W1, b1, W2, b2,
                                                       slots, (float*)d_out);
    }
}

// Round 7
// 626.007 us; speedup vs baseline: 1.9483x; 1.1963x over previous
//
#include <hip/hip_runtime.h>
#include <hip/hip_bf16.h>

#define B_ 64
#define N_ 4096
#define C_ 256
#define K_ 8
#define M_ (B_*N_)
#define ITERS_ 3
#define SCALE_ 0.0625f
#define EPS_ 1e-8f

typedef __attribute__((ext_vector_type(4))) float f32x4;
typedef __attribute__((ext_vector_type(8))) unsigned short ushort8;

static __device__ __forceinline__ unsigned short f2bf(float f){
    union { float f; unsigned u; } v; v.f = f;
    unsigned r = v.u + 0x7fffu + ((v.u >> 16) & 1u);
    return (unsigned short)(r >> 16);
}
static __device__ __forceinline__ float bf2f(unsigned short h){
    union { unsigned u; float f; } v; v.u = ((unsigned)h) << 16;
    return v.f;
}

// ---------------- prep1: slots init ----------------
__global__ void prep1_kernel(const float* __restrict__ mu, const float* __restrict__ lsig,
                             const float* __restrict__ noise, float* __restrict__ slots){
    int idx = blockIdx.x*256 + threadIdx.x;   // 0..131071
    int c = idx & 255, i = (idx >> 8) & 7;
    slots[idx] = mu[c] + expf(lsig[c])*noise[i*256 + c];
}

// ---------------- prep2: WqkT = Wq@Wk^T, bqt = bq@Wk^T, wqb = Wq@bk, bqk = bq.bk ----------------
__global__ void prep2_kernel(const float* __restrict__ Wq, const float* __restrict__ Wk,
                             const float* __restrict__ bq, const float* __restrict__ bk,
                             float* __restrict__ WqkT, float* __restrict__ bqt,
                             float* __restrict__ wqb, float* __restrict__ bqkv){
    __shared__ float wqrow[256], bkl[256], bql[256];
    __shared__ float red[4], red2[4];
    const int t = threadIdx.x, c = blockIdx.x;
    wqrow[t] = Wq[(size_t)c*256 + t];
    bkl[t] = bk[t];
    bql[t] = bq[t];
    __syncthreads();
    float acc = 0.f, accb = 0.f;
    const float* wkr = Wk + (size_t)t*256;
    #pragma unroll 4
    for (int d = 0; d < 256; d += 4){
        float4 wk4 = *(const float4*)(wkr + d);
        float4 wq4 = *(const float4*)(&wqrow[d]);
        float4 bq4 = *(const float4*)(&bql[d]);
        acc  += wq4.x*wk4.x + wq4.y*wk4.y + wq4.z*wk4.z + wq4.w*wk4.w;
        accb += bq4.x*wk4.x + bq4.y*wk4.y + bq4.z*wk4.z + bq4.w*wk4.w;
    }
    WqkT[(size_t)c*256 + t] = acc;
    if (c == 0) bqt[t] = accb;
    float pw = wqrow[t]*bkl[t];
    float pb = bql[t]*bkl[t];
    #pragma unroll
    for (int m = 1; m < 64; m <<= 1){ pw += __shfl_xor(pw, m); pb += __shfl_xor(pb, m); }
    if ((t & 63) == 0){ red[t >> 6] = pw; red2[t >> 6] = pb; }
    __syncthreads();
    if (t == 0){
        wqb[c] = red[0] + red[1] + red[2] + red[3];
        if (c == 0) bqkv[0] = red2[0] + red2[1] + red2[2] + red2[3];
    }
}

// ---------------- x -> x_hat bf16; layout XH[jt][og(0..7)][rloc(0..255)][32c] ----------------
__global__ void ln_kernel(const float* __restrict__ x, const float* __restrict__ g,
                          const float* __restrict__ bta, unsigned short* __restrict__ XH){
    const int t = threadIdx.x;
    const int row = blockIdx.x*32 + (t >> 3), sl = t & 7;
    const float* xr = x + (size_t)row*C_ + sl*32;
    float v[32];
    #pragma unroll
    for (int q = 0; q < 8; ++q) *(float4*)&v[q*4] = *(const float4*)(xr + q*4);
    float sum = 0.f, sq = 0.f;
    #pragma unroll
    for (int e = 0; e < 32; ++e){ sum += v[e]; sq += v[e]*v[e]; }
    #pragma unroll
    for (int m = 1; m < 8; m <<= 1){ sum += __shfl_xor(sum, m); sq += __shfl_xor(sq, m); }
    float mean = sum * (1.f/256.f);
    float rstd = rsqrtf(sq * (1.f/256.f) - mean*mean + 1e-5f);
    const int jt = row >> 8, rloc = row & 255;
    unsigned short* dst = XH + (((size_t)jt*8 + sl)*256 + rloc)*32;
    #pragma unroll
    for (int u = 0; u < 4; ++u){
        float4 g0 = *(const float4*)(g + sl*32 + u*8);
        float4 g1 = *(const float4*)(g + sl*32 + u*8 + 4);
        float4 b0 = *(const float4*)(bta + sl*32 + u*8);
        float4 b1 = *(const float4*)(bta + sl*32 + u*8 + 4);
        const float* gp0 = (const float*)&g0; const float* gp1 = (const float*)&g1;
        const float* bp0 = (const float*)&b0; const float* bp1 = (const float*)&b1;
        ushort8 pk;
        #pragma unroll
        for (int e = 0; e < 4; ++e){
            pk[e]   = f2bf((v[u*8+e]   - mean)*rstd*gp0[e] + bp0[e]);
            pk[4+e] = f2bf((v[u*8+4+e] - mean)*rstd*gp1[e] + bp1[e]);
        }
        *(ushort8*)(dst + u*8) = pk;
    }
}

// ---------------- per-iter: slotq = LN_s + q~ = SCALE*(sn@Wqk + bqt), qb  (grid (B,4), 512) ----------------
__global__ void slotq_kernel(const float* __restrict__ slots, const float* __restrict__ WqkT,
                             const float* __restrict__ bqt, const float* __restrict__ wqb,
                             const float* __restrict__ bqkv, const float* __restrict__ gs,
                             const float* __restrict__ bs, float* __restrict__ qtbuf,
                             float* __restrict__ qbb){
    __shared__ float sn[8][260];
    const int t = threadIdx.x, b = blockIdx.x, cgb = blockIdx.y;
    const int i = t >> 6, l = t & 63;
    {
        float4 v4 = *(const float4*)(slots + ((size_t)b*8 + i)*256 + l*4);
        float sum = v4.x + v4.y + v4.z + v4.w;
        float sq  = v4.x*v4.x + v4.y*v4.y + v4.z*v4.z + v4.w*v4.w;
        #pragma unroll
        for (int m = 1; m < 64; m <<= 1){ sum += __shfl_xor(sum, m); sq += __shfl_xor(sq, m); }
        float mean = sum * (1.f/256.f);
        float rstd = rsqrtf(sq * (1.f/256.f) - mean*mean + 1e-5f);
        float4 g4 = *(const float4*)(gs + l*4);
        float4 b4 = *(const float4*)(bs + l*4);
        float n0 = (v4.x - mean)*rstd*g4.x + b4.x;
        float n1 = (v4.y - mean)*rstd*g4.y + b4.y;
        float n2 = (v4.z - mean)*rstd*g4.z + b4.z;
        float n3 = (v4.w - mean)*rstd*g4.w + b4.w;
        sn[i][l*4+0] = n0; sn[i][l*4+1] = n1; sn[i][l*4+2] = n2; sn[i][l*4+3] = n3;
        if (cgb == 0){
            float4 w4 = *(const float4*)(wqb + l*4);
            float pb = n0*w4.x + n1*w4.y + n2*w4.z + n3*w4.w;
            #pragma unroll
            for (int m = 1; m < 64; m <<= 1) pb += __shfl_xor(pb, m);
            if (l == 0) qbb[(size_t)b*8 + i] = SCALE_*(pb + bqkv[0]);
        }
    }
    __syncthreads();
    const int col = cgb*64 + l;
    float acc = bqt[col];
    // chunked streaming: 64 independent scalar loads in flight per batch
    #pragma unroll
    for (int cb = 0; cb < 256; cb += 64){
        float w[64];
        #pragma unroll
        for (int u = 0; u < 64; ++u) w[u] = WqkT[(size_t)(cb+u)*256 + col];
        #pragma unroll
        for (int u = 0; u < 64; ++u) acc += sn[i][cb+u]*w[u];
    }
    qtbuf[((size_t)b*8 + i)*256 + col] = SCALE_*acc;
}

// ---------------- per-iter: fused attn (QK + softmax + PV, single x_hat pass)  (grid (B,16), 256) ----------------
__global__ void attn_kernel(const unsigned short* __restrict__ XH, const float* __restrict__ qt,
                            const float* __restrict__ qb, float* __restrict__ Spart,
                            float* __restrict__ Upart){
    __shared__ __align__(16) unsigned short xs[2*8192];   // 2 x 32rows x 256c, swizzled
    __shared__ __align__(16) float qts2[8*292 + 4];       // q~ padded: [cs]*292 + i*36 + e
    __shared__ float qbs[8];
    __shared__ __align__(16) unsigned short ps[32*8];     // p bf16 for current chunk [j][i]
    __shared__ float swred[4][8];
    const int t = threadIdx.x, b = blockIdx.x, jb = blockIdx.y;
    const unsigned short* XB = XH + (size_t)(b*16 + jb)*65536;
    {
        const int i = t >> 5, c0 = (t & 31)*8;
        const float* qp = qt + ((size_t)b*8 + i)*256 + c0;
        float4 a0 = *(const float4*)qp;
        float4 a1 = *(const float4*)(qp + 4);
        float* dst = &qts2[(c0 >> 5)*292 + i*36 + (c0 & 31)];
        *(float4*)dst = a0;
        *(float4*)(dst + 4) = a1;
        if ((t & 31) == 0) qbs[i] = qb[(size_t)b*8 + i];
    }
    const int og = t >> 5, r = t & 31;
    const int ssw = (r & 7) << 3;
    ushort8 s0, s1, s2, s3;
    {
        const unsigned short* g0 = XB + ((size_t)og*256 + r)*32;
        s0 = *(const ushort8*)(g0);      s1 = *(const ushort8*)(g0 + 8);
        s2 = *(const ushort8*)(g0 + 16); s3 = *(const ushort8*)(g0 + 24);
    }
    {
        unsigned short* xw = &xs[r*256];
        *(ushort8*)&xw[(og*32 +  0) ^ ssw] = s0;
        *(ushort8*)&xw[(og*32 +  8) ^ ssw] = s1;
        *(ushort8*)&xw[(og*32 + 16) ^ ssw] = s2;
        *(ushort8*)&xw[(og*32 + 24) ^ ssw] = s3;
    }
    __syncthreads();

    const int jl = t >> 3, cs = t & 7;
    const int jsw = (jl & 7) << 3;
    const int csb = cs*292;
    const int islot = t >> 5, cg = t & 31;
    f32x4 u0 = (f32x4){0.f,0.f,0.f,0.f}, u1 = (f32x4){0.f,0.f,0.f,0.f};
    float s8a[8] = {0.f,0.f,0.f,0.f,0.f,0.f,0.f,0.f};

    for (int ch = 0; ch < 8; ++ch){
        const int cur = (ch & 1) << 13;
        if (ch < 7){
            const unsigned short* g1 = XB + ((size_t)og*256 + (ch+1)*32 + r)*32;
            s0 = *(const ushort8*)(g1);      s1 = *(const ushort8*)(g1 + 8);
            s2 = *(const ushort8*)(g1 + 16); s3 = *(const ushort8*)(g1 + 24);
        }
        // ---- QK: thread (jl, cs) covers c in [cs*32, +32) of row jl ----
        float pd[8] = {0.f,0.f,0.f,0.f,0.f,0.f,0.f,0.f};
        const unsigned short* xrow = &xs[cur + jl*256];
        #pragma unroll
        for (int k = 0; k < 4; ++k){
            ushort8 xv = *(const ushort8*)&xrow[(cs*32 + k*8) ^ jsw];
            float xf0 = bf2f(xv[0]), xf1 = bf2f(xv[1]), xf2 = bf2f(xv[2]), xf3 = bf2f(xv[3]);
            float xf4 = bf2f(xv[4]), xf5 = bf2f(xv[5]), xf6 = bf2f(xv[6]), xf7 = bf2f(xv[7]);
            #pragma unroll
            for (int i = 0; i < 8; ++i){
                const float* qp2 = &qts2[csb + i*36 + k*8];
                float4 qa = *(const float4*)qp2;
                float4 qc = *(const float4*)(qp2 + 4);
                pd[i] += qa.x*xf0 + qa.y*xf1 + qa.z*xf2 + qa.w*xf3
                       + qc.x*xf4 + qc.y*xf5 + qc.z*xf6 + qc.w*xf7;
            }
        }
        float p[8];
        {
            float d8[8];
            #pragma unroll
            for (int i = 0; i < 8; ++i){
                float v = pd[i];
                v += __shfl_xor(v, 1);
                v += __shfl_xor(v, 2);
                v += __shfl_xor(v, 4);
                d8[i] = v + qbs[i];
            }
            float mx = d8[0];
            #pragma unroll
            for (int i = 1; i < 8; ++i) mx = fmaxf(mx, d8[i]);
            float se = 0.f;
            #pragma unroll
            for (int i = 0; i < 8; ++i){ p[i] = __expf(d8[i] - mx); se += p[i]; }
            float inv = 1.f / se;
            #pragma unroll
            for (int i = 0; i < 8; ++i){ p[i] = p[i]*inv + EPS_; s8a[i] += p[i]; }
        }
        if (cs == 0){
            ushort8 pp;
            #pragma unroll
            for (int i = 0; i < 8; ++i) pp[i] = f2bf(p[i]);
            *(ushort8*)&ps[jl*8] = pp;
        }
        if (ch < 7){
            unsigned short* xw = &xs[(cur ^ 8192) + r*256];
            *(ushort8*)&xw[(og*32 +  0) ^ ssw] = s0;
            *(ushort8*)&xw[(og*32 +  8) ^ ssw] = s1;
            *(ushort8*)&xw[(og*32 + 16) ^ ssw] = s2;
            *(ushort8*)&xw[(og*32 + 24) ^ ssw] = s3;
        }
        __syncthreads();
        // ---- PV: thread (islot, cg) accumulates u over this chunk's 32 rows ----
        #pragma unroll 4
        for (int jj = 0; jj < 32; ++jj){
            float pw = bf2f(ps[jj*8 + islot]);
            ushort8 vv = *(const ushort8*)&xs[cur + jj*256 + ((cg*8) ^ ((jj & 7) << 3))];
            u0[0] += pw*bf2f(vv[0]); u0[1] += pw*bf2f(vv[1]);
            u0[2] += pw*bf2f(vv[2]); u0[3] += pw*bf2f(vv[3]);
            u1[0] += pw*bf2f(vv[4]); u1[1] += pw*bf2f(vv[5]);
            u1[2] += pw*bf2f(vv[6]); u1[3] += pw*bf2f(vv[7]);
        }
        __syncthreads();
    }
    {
        #pragma unroll
        for (int i = 0; i < 8; ++i){
            float v = s8a[i];
            #pragma unroll
            for (int m = 1; m < 64; m <<= 1) v += __shfl_xor(v, m);
            if ((t & 63) == 0) swred[t >> 6][i] = v;
        }
        __syncthreads();
        if (t < 8)
            Spart[((size_t)(b*16 + jb))*8 + t] =
                (swred[0][t] + swred[1][t] + swred[2][t] + swred[3][t]) * 0.125f;
    }
    {
        float* up = Upart + (((size_t)(b*16 + jb))*8 + islot)*256 + cg*8;
        float4 o0; o0.x = u0[0]; o0.y = u0[1]; o0.z = u0[2]; o0.w = u0[3];
        float4 o1; o1.x = u1[0]; o1.y = u1[1]; o1.z = u1[2]; o1.w = u1[3];
        *(float4*)up       = o0;
        *(float4*)(up + 4) = o1;
    }
}

// ---------------- per-iter: slotu1 = Upart reduce + Wv GEMM + GRU n-slice  (grid (B,4), 512) ----------------
__global__ void slotu1_kernel(const float* __restrict__ slots, const float* __restrict__ Spart,
                              const float* __restrict__ Upart, const float* __restrict__ Wv,
                              const float* __restrict__ bv, const float* __restrict__ W_ih,
                              const float* __restrict__ b_ih, const float* __restrict__ W_hh,
                              const float* __restrict__ b_hh, float* __restrict__ slots2){
    __shared__ float us[8][260], sp[8][260], upd[8][260];
    const int t = threadIdx.x, b = blockIdx.x, ng = blockIdx.y;
    const int i = t >> 6, l = t & 63;
    {
        float a0 = 0.f, a1 = 0.f, a2 = 0.f, a3 = 0.f, S = 0.f;
        #pragma unroll
        for (int jbl = 0; jbl < 16; ++jbl){
            float4 u4 = *(const float4*)(Upart + (((size_t)(b*16 + jbl))*8 + i)*256 + l*4);
            a0 += u4.x; a1 += u4.y; a2 += u4.z; a3 += u4.w;
            S += Spart[((size_t)(b*16 + jbl))*8 + i];
        }
        float invS = 1.f / S;
        us[i][l*4+0] = a0*invS; us[i][l*4+1] = a1*invS;
        us[i][l*4+2] = a2*invS; us[i][l*4+3] = a3*invS;
        float4 s4 = *(const float4*)(slots + ((size_t)b*8 + i)*256 + l*4);
        sp[i][l*4+0] = s4.x; sp[i][l*4+1] = s4.y; sp[i][l*4+2] = s4.z; sp[i][l*4+3] = s4.w;
    }
    __syncthreads();
    {   // upd = us @ Wv + bv (full width, redundant across ng blocks), chunked streaming
        const int c4 = l*4;
        float4 acc = *(const float4*)(bv + c4);
        #pragma unroll
        for (int cb = 0; cb < 256; cb += 16){
            float4 w4[16];
            #pragma unroll
            for (int u = 0; u < 16; ++u)
                w4[u] = *(const float4*)(Wv + (size_t)(cb+u)*256 + c4);
            #pragma unroll
            for (int u = 0; u < 16; ++u){
                float uv = us[i][cb+u];
                acc.x += uv*w4[u].x; acc.y += uv*w4[u].y;
                acc.z += uv*w4[u].z; acc.w += uv*w4[u].w;
            }
        }
        *(float4*)&upd[i][c4] = acc;
    }
    __syncthreads();
    {   // GRU for n-slice, 6 streams chunked 8 deep (48 loads in flight)
        const int n = ng*64 + l;
        float xr = b_ih[n], xz = b_ih[256+n], xn = b_ih[512+n];
        float hr = b_hh[n], hz = b_hh[256+n], hn = b_hh[512+n];
        #pragma unroll 2
        for (int cb = 0; cb < 256; cb += 8){
            float wi0[8], wi1[8], wi2[8], wh0[8], wh1[8], wh2[8];
            #pragma unroll
            for (int u = 0; u < 8; ++u){
                const float* wi = W_ih + (size_t)(cb+u)*768 + n;
                const float* wh = W_hh + (size_t)(cb+u)*768 + n;
                wi0[u] = wi[0]; wi1[u] = wi[256]; wi2[u] = wi[512];
                wh0[u] = wh[0]; wh1[u] = wh[256]; wh2[u] = wh[512];
            }
            #pragma unroll
            for (int u = 0; u < 8; ++u){
                float uv = upd[i][cb+u], sv = sp[i][cb+u];
                xr += uv*wi0[u]; xz += uv*wi1[u]; xn += uv*wi2[u];
                hr += sv*wh0[u]; hz += sv*wh1[u]; hn += sv*wh2[u];
            }
        }
        float rv = 1.f/(1.f + __expf(-(xr + hr)));
        float zv = 1.f/(1.f + __expf(-(xz + hz)));
        float nn = tanhf(xn + rv*hn);
        slots2[((size_t)b*8 + i)*256 + n] = (1.f - zv)*nn + zv*sp[i][n];
    }
}

// ---------------- per-iter: slotu2 = LN_ff + FFN1 + FFN2 n-slice  (grid (B,4), 512) ----------------
__global__ void slotu2_kernel(const float* __restrict__ slots2, const float* __restrict__ gf,
                              const float* __restrict__ bf, const float* __restrict__ W1,
                              const float* __restrict__ b1, const float* __restrict__ W2,
                              const float* __restrict__ b2, float* __restrict__ slots,
                              float* __restrict__ dout){
    __shared__ float s0[8][260], pre[8][260], hb[8][260];
    const int t = threadIdx.x, b = blockIdx.x, ng = blockIdx.y;
    const int i = t >> 6, l = t & 63;
    {
        float4 v4 = *(const float4*)(slots2 + ((size_t)b*8 + i)*256 + l*4);
        float sum = v4.x + v4.y + v4.z + v4.w;
        float sq  = v4.x*v4.x + v4.y*v4.y + v4.z*v4.z + v4.w*v4.w;
        #pragma unroll
        for (int m = 1; m < 64; m <<= 1){ sum += __shfl_xor(sum, m); sq += __shfl_xor(sq, m); }
        float mean = sum * (1.f/256.f);
        float rstd = rsqrtf(sq * (1.f/256.f) - mean*mean + 1e-5f);
        float4 g4 = *(const float4*)(gf + l*4);
        float4 b4 = *(const float4*)(bf + l*4);
        s0[i][l*4+0] = v4.x; s0[i][l*4+1] = v4.y; s0[i][l*4+2] = v4.z; s0[i][l*4+3] = v4.w;
        pre[i][l*4+0] = (v4.x - mean)*rstd*g4.x + b4.x;
        pre[i][l*4+1] = (v4.y - mean)*rstd*g4.y + b4.y;
        pre[i][l*4+2] = (v4.z - mean)*rstd*g4.z + b4.z;
        pre[i][l*4+3] = (v4.w - mean)*rstd*g4.w + b4.w;
    }
    __syncthreads();
    {   // h = relu(pre @ W1 + b1) (full width, redundant), chunked streaming
        const int h4 = l*4;
        float4 acc = *(const float4*)(b1 + h4);
        #pragma unroll
        for (int cb = 0; cb < 256; cb += 16){
            float4 w4[16];
            #pragma unroll
            for (int u = 0; u < 16; ++u)
                w4[u] = *(const float4*)(W1 + (size_t)(cb+u)*256 + h4);
            #pragma unroll
            for (int u = 0; u < 16; ++u){
                float pv = pre[i][cb+u];
                acc.x += pv*w4[u].x; acc.y += pv*w4[u].y;
                acc.z += pv*w4[u].z; acc.w += pv*w4[u].w;
            }
        }
        hb[i][h4+0] = fmaxf(acc.x, 0.f); hb[i][h4+1] = fmaxf(acc.y, 0.f);
        hb[i][h4+2] = fmaxf(acc.z, 0.f); hb[i][h4+3] = fmaxf(acc.w, 0.f);
    }
    __syncthreads();
    {   // out = s0 + h @ W2 + b2, n-slice, chunked streaming
        const int n = ng*64 + l;
        float acc = b2[n];
        #pragma unroll
        for (int mb = 0; mb < 256; mb += 64){
            float w[64];
            #pragma unroll
            for (int u = 0; u < 64; ++u) w[u] = W2[(size_t)(mb+u)*256 + n];
            #pragma unroll
            for (int u = 0; u < 64; ++u) acc += hb[i][mb+u]*w[u];
        }
        float val = s0[i][n] + acc;
        size_t off = ((size_t)b*8 + i)*256 + n;
        slots[off] = val;
        dout[off]  = val;
    }
}

extern "C" void kernel_launch(void* const* d_in, const int* in_sizes, int n_in,
                              void* d_out, int out_size, void* d_ws, size_t ws_size,
                              hipStream_t stream){
    const float* inputs = (const float*)d_in[0];
    const float* noise  = (const float*)d_in[1];
    const float* mu     = (const float*)d_in[2];
    const float* lsig   = (const float*)d_in[3];
    const float* g_in   = (const float*)d_in[4];
    const float* b_in   = (const float*)d_in[5];
    const float* g_s    = (const float*)d_in[6];
    const float* b_s    = (const float*)d_in[7];
    const float* g_ff   = (const float*)d_in[8];
    const float* b_ff   = (const float*)d_in[9];
    const float* Wq     = (const float*)d_in[10];
    const float* bq     = (const float*)d_in[11];
    const float* Wk     = (const float*)d_in[12];
    const float* bk     = (const float*)d_in[13];
    const float* Wv     = (const float*)d_in[14];
    const float* bv     = (const float*)d_in[15];
    const float* W_ih   = (const float*)d_in[16];
    const float* b_ih   = (const float*)d_in[17];
    const float* W_hh   = (const float*)d_in[18];
    const float* b_hh   = (const float*)d_in[19];
    const float* W1     = (const float*)d_in[20];
    const float* b1     = (const float*)d_in[21];
    const float* W2     = (const float*)d_in[22];
    const float* b2     = (const float*)d_in[23];

    char* ws = (char*)d_ws;
    unsigned short* XH  = (unsigned short*)(ws);               // 128 MB
    float* Upart        = (float*)(ws + ((size_t)128 << 20));  // 8 MB
    float* Spart        = (float*)(ws + ((size_t)136 << 20));  // 8 KB
    float* qtbuf        = (float*)(ws + ((size_t)137 << 20));  // 512 KB
    float* qbb          = (float*)(ws + ((size_t)138 << 20));  // 2 KB
    float* slots        = (float*)(ws + ((size_t)139 << 20));  // 512 KB
    float* slots2       = (float*)(ws + ((size_t)140 << 20));  // 512 KB
    float* WqkT         = (float*)(ws + ((size_t)141 << 20));  // 256 KB
    float* bqt          = (float*)(ws + ((size_t)142 << 20));  // 1 KB
    float* wqb          = (float*)(ws + ((size_t)143 << 20));  // 1 KB
    float* bqkv         = (float*)(ws + ((size_t)144 << 20));  // 4 B

    prep1_kernel<<<512, 256, 0, stream>>>(mu, lsig, noise, slots);
    prep2_kernel<<<256, 256, 0, stream>>>(Wq, Wk, bq, bk, WqkT, bqt, wqb, bqkv);
    ln_kernel<<<M_/32, 256, 0, stream>>>(inputs, g_in, b_in, XH);
    for (int it = 0; it < ITERS_; ++it){
        slotq_kernel<<<dim3(B_, 4), 512, 0, stream>>>(slots, WqkT, bqt, wqb, bqkv,
                                                      g_s, b_s, qtbuf, qbb);
        attn_kernel<<<dim3(B_, 16), 256, 0, stream>>>(XH, qtbuf, qbb, Spart, Upart);
        slotu1_kernel<<<dim3(B_, 4), 512, 0, stream>>>(slots, Spart, Upart, Wv, bv,
                                                       W_ih, b_ih, W_hh, b_hh, slots2);
        slotu2_kernel<<<dim3(B_, 4), 512, 0, stream>>>(slots2, g_ff, b_ff, W1, b1, W2, b2,
                                                       slots, (float*)d_out);
    }
}

// Round 8
// 552.812 us; speedup vs baseline: 2.2063x; 1.1324x over previous
//
#include <hip/hip_runtime.h>
#include <hip/hip_bf16.h>

#define B_ 64
#define N_ 4096
#define C_ 256
#define K_ 8
#define M_ (B_*N_)
#define ITERS_ 3
#define SCALE_ 0.0625f
#define EPS_ 1e-8f

typedef __attribute__((ext_vector_type(4))) float f32x4;
typedef __attribute__((ext_vector_type(8))) __bf16 bf16x8;
typedef __attribute__((ext_vector_type(8))) unsigned short ushort8;

static __device__ __forceinline__ unsigned short f2bf(float f){
    union { float f; unsigned u; } v; v.f = f;
    unsigned r = v.u + 0x7fffu + ((v.u >> 16) & 1u);
    return (unsigned short)(r >> 16);
}
static __device__ __forceinline__ float bf2f(unsigned short h){
    union { unsigned u; float f; } v; v.u = ((unsigned)h) << 16;
    return v.f;
}

// ---------------- prep1: slots init ----------------
__global__ void prep1_kernel(const float* __restrict__ mu, const float* __restrict__ lsig,
                             const float* __restrict__ noise, float* __restrict__ slots){
    int idx = blockIdx.x*256 + threadIdx.x;   // 0..131071
    int c = idx & 255, i = (idx >> 8) & 7;
    slots[idx] = mu[c] + expf(lsig[c])*noise[i*256 + c];
}

// ---------------- prep2: WqkT = Wq@Wk^T, bqt = bq@Wk^T, wqb = Wq@bk, bqk = bq.bk ----------------
__global__ void prep2_kernel(const float* __restrict__ Wq, const float* __restrict__ Wk,
                             const float* __restrict__ bq, const float* __restrict__ bk,
                             float* __restrict__ WqkT, float* __restrict__ bqt,
                             float* __restrict__ wqb, float* __restrict__ bqkv){
    __shared__ float wqrow[256], bkl[256], bql[256];
    __shared__ float red[4], red2[4];
    const int t = threadIdx.x, c = blockIdx.x;
    wqrow[t] = Wq[(size_t)c*256 + t];
    bkl[t] = bk[t];
    bql[t] = bq[t];
    __syncthreads();
    float acc = 0.f, accb = 0.f;
    const float* wkr = Wk + (size_t)t*256;
    #pragma unroll 4
    for (int d = 0; d < 256; d += 4){
        float4 wk4 = *(const float4*)(wkr + d);
        float4 wq4 = *(const float4*)(&wqrow[d]);
        float4 bq4 = *(const float4*)(&bql[d]);
        acc  += wq4.x*wk4.x + wq4.y*wk4.y + wq4.z*wk4.z + wq4.w*wk4.w;
        accb += bq4.x*wk4.x + bq4.y*wk4.y + bq4.z*wk4.z + bq4.w*wk4.w;
    }
    WqkT[(size_t)c*256 + t] = acc;
    if (c == 0) bqt[t] = accb;
    float pw = wqrow[t]*bkl[t];
    float pb = bql[t]*bkl[t];
    #pragma unroll
    for (int m = 1; m < 64; m <<= 1){ pw += __shfl_xor(pw, m); pb += __shfl_xor(pb, m); }
    if ((t & 63) == 0){ red[t >> 6] = pw; red2[t >> 6] = pb; }
    __syncthreads();
    if (t == 0){
        wqb[c] = red[0] + red[1] + red[2] + red[3];
        if (c == 0) bqkv[0] = red2[0] + red2[1] + red2[2] + red2[3];
    }
}

// ---------------- x -> x_hat bf16; layout XH[jt][og(0..7)][rloc(0..255)][32c] ----------------
__global__ void ln_kernel(const float* __restrict__ x, const float* __restrict__ g,
                          const float* __restrict__ bta, unsigned short* __restrict__ XH){
    const int t = threadIdx.x;
    const int row = blockIdx.x*32 + (t >> 3), sl = t & 7;
    const float* xr = x + (size_t)row*C_ + sl*32;
    float v[32];
    #pragma unroll
    for (int q = 0; q < 8; ++q) *(float4*)&v[q*4] = *(const float4*)(xr + q*4);
    float sum = 0.f, sq = 0.f;
    #pragma unroll
    for (int e = 0; e < 32; ++e){ sum += v[e]; sq += v[e]*v[e]; }
    #pragma unroll
    for (int m = 1; m < 8; m <<= 1){ sum += __shfl_xor(sum, m); sq += __shfl_xor(sq, m); }
    float mean = sum * (1.f/256.f);
    float rstd = rsqrtf(sq * (1.f/256.f) - mean*mean + 1e-5f);
    const int jt = row >> 8, rloc = row & 255;
    unsigned short* dst = XH + (((size_t)jt*8 + sl)*256 + rloc)*32;
    #pragma unroll
    for (int u = 0; u < 4; ++u){
        float4 g0 = *(const float4*)(g + sl*32 + u*8);
        float4 g1 = *(const float4*)(g + sl*32 + u*8 + 4);
        float4 b0 = *(const float4*)(bta + sl*32 + u*8);
        float4 b1 = *(const float4*)(bta + sl*32 + u*8 + 4);
        const float* gp0 = (const float*)&g0; const float* gp1 = (const float*)&g1;
        const float* bp0 = (const float*)&b0; const float* bp1 = (const float*)&b1;
        ushort8 pk;
        #pragma unroll
        for (int e = 0; e < 4; ++e){
            pk[e]   = f2bf((v[u*8+e]   - mean)*rstd*gp0[e] + bp0[e]);
            pk[4+e] = f2bf((v[u*8+4+e] - mean)*rstd*gp1[e] + bp1[e]);
        }
        *(ushort8*)(dst + u*8) = pk;
    }
}

// ---------------- per-iter: slotq = LN_s + q~ = SCALE*(sn@Wqk + bqt), qb  (grid (B,4), 512) ----------------
__global__ void slotq_kernel(const float* __restrict__ slots, const float* __restrict__ WqkT,
                             const float* __restrict__ bqt, const float* __restrict__ wqb,
                             const float* __restrict__ bqkv, const float* __restrict__ gs,
                             const float* __restrict__ bs, float* __restrict__ qtbuf,
                             float* __restrict__ qbb){
    __shared__ float sn[8][260];
    const int t = threadIdx.x, b = blockIdx.x, cgb = blockIdx.y;
    const int i = t >> 6, l = t & 63;
    {
        float4 v4 = *(const float4*)(slots + ((size_t)b*8 + i)*256 + l*4);
        float sum = v4.x + v4.y + v4.z + v4.w;
        float sq  = v4.x*v4.x + v4.y*v4.y + v4.z*v4.z + v4.w*v4.w;
        #pragma unroll
        for (int m = 1; m < 64; m <<= 1){ sum += __shfl_xor(sum, m); sq += __shfl_xor(sq, m); }
        float mean = sum * (1.f/256.f);
        float rstd = rsqrtf(sq * (1.f/256.f) - mean*mean + 1e-5f);
        float4 g4 = *(const float4*)(gs + l*4);
        float4 b4 = *(const float4*)(bs + l*4);
        float n0 = (v4.x - mean)*rstd*g4.x + b4.x;
        float n1 = (v4.y - mean)*rstd*g4.y + b4.y;
        float n2 = (v4.z - mean)*rstd*g4.z + b4.z;
        float n3 = (v4.w - mean)*rstd*g4.w + b4.w;
        sn[i][l*4+0] = n0; sn[i][l*4+1] = n1; sn[i][l*4+2] = n2; sn[i][l*4+3] = n3;
        if (cgb == 0){
            float4 w4 = *(const float4*)(wqb + l*4);
            float pb = n0*w4.x + n1*w4.y + n2*w4.z + n3*w4.w;
            #pragma unroll
            for (int m = 1; m < 64; m <<= 1) pb += __shfl_xor(pb, m);
            if (l == 0) qbb[(size_t)b*8 + i] = SCALE_*(pb + bqkv[0]);
        }
    }
    __syncthreads();
    const int col = cgb*64 + l;
    float acc = bqt[col];
    #pragma unroll
    for (int cb = 0; cb < 256; cb += 64){
        float w[64];
        #pragma unroll
        for (int u = 0; u < 64; ++u) w[u] = WqkT[(size_t)(cb+u)*256 + col];
        #pragma unroll
        for (int u = 0; u < 64; ++u) acc += sn[i][cb+u]*w[u];
    }
    qtbuf[((size_t)b*8 + i)*256 + col] = SCALE_*acc;
}

// ---------------- per-iter: fused attn — MFMA QK + in-frag softmax + VALU PV  (grid (B,16), 256) ----------------
__global__ void attn_kernel(const unsigned short* __restrict__ XH, const float* __restrict__ qt,
                            const float* __restrict__ qb, float* __restrict__ Spart,
                            float* __restrict__ Upart){
    __shared__ __align__(16) unsigned short xs[2*8192];   // 2 x 32rows x 256c, swizzled (32 KB)
    __shared__ __align__(16) unsigned short ps[32*8];     // p bf16 for current chunk [j][i]
    __shared__ float swred[2][8];
    const int t = threadIdx.x, b = blockIdx.x, jb = blockIdx.y;
    const unsigned short* XB = XH + (size_t)(b*16 + jb)*65536;
    const int wv = t >> 6, l = t & 63;
    const int bi = l & 15, kg = l >> 4;

    // B-fragments: q~ held in registers for the whole kernel (waves 0-1 only)
    bf16x8 bfrag[8];
    float qbl = 0.f;
    {
        const ushort8 zz = (ushort8){0,0,0,0,0,0,0,0};
        #pragma unroll
        for (int ks = 0; ks < 8; ++ks) bfrag[ks] = __builtin_bit_cast(bf16x8, zz);
        if (wv < 2 && bi < 8){
            #pragma unroll
            for (int ks = 0; ks < 8; ++ks){
                const float* qp = qt + ((size_t)b*8 + bi)*256 + ks*32 + kg*8;
                float4 qa = *(const float4*)qp;
                float4 qc = *(const float4*)(qp + 4);
                ushort8 pk;
                pk[0]=f2bf(qa.x); pk[1]=f2bf(qa.y); pk[2]=f2bf(qa.z); pk[3]=f2bf(qa.w);
                pk[4]=f2bf(qc.x); pk[5]=f2bf(qc.y); pk[6]=f2bf(qc.z); pk[7]=f2bf(qc.w);
                bfrag[ks] = __builtin_bit_cast(bf16x8, pk);
            }
            qbl = qb[(size_t)b*8 + bi];
        }
    }

    // stage chunk 0
    const int og = t >> 5, r = t & 31;
    const int ssw = (r & 7) << 3;
    ushort8 s0, s1, s2, s3;
    {
        const unsigned short* g0 = XB + ((size_t)og*256 + r)*32;
        s0 = *(const ushort8*)(g0);      s1 = *(const ushort8*)(g0 + 8);
        s2 = *(const ushort8*)(g0 + 16); s3 = *(const ushort8*)(g0 + 24);
    }
    {
        unsigned short* xw = &xs[r*256];
        *(ushort8*)&xw[(og*32 +  0) ^ ssw] = s0;
        *(ushort8*)&xw[(og*32 +  8) ^ ssw] = s1;
        *(ushort8*)&xw[(og*32 + 16) ^ ssw] = s2;
        *(ushort8*)&xw[(og*32 + 24) ^ ssw] = s3;
    }
    __syncthreads();

    const int islot = t >> 5, cg = t & 31;
    f32x4 u0 = (f32x4){0.f,0.f,0.f,0.f}, u1 = (f32x4){0.f,0.f,0.f,0.f};
    float s8loc = 0.f;

    for (int ch = 0; ch < 8; ++ch){
        const int cur = (ch & 1) << 13;
        if (ch < 7){
            const unsigned short* g1 = XB + ((size_t)og*256 + (ch+1)*32 + r)*32;
            s0 = *(const ushort8*)(g1);      s1 = *(const ushort8*)(g1 + 8);
            s2 = *(const ushort8*)(g1 + 16); s3 = *(const ushort8*)(g1 + 24);
        }
        // ---- QK via MFMA: wave wv<2 computes its 16-row tile ----
        if (wv < 2){
            f32x4 acc = (f32x4){0.f,0.f,0.f,0.f};
            const int rowL = wv*16 + bi;
            const unsigned short* xrow = &xs[cur + rowL*256];
            #pragma unroll
            for (int ks = 0; ks < 8; ++ks){
                int chn = (ks*4 + kg) ^ (rowL & 7);
                bf16x8 af = *(const bf16x8*)&xrow[chn*8];
                acc = __builtin_amdgcn_mfma_f32_16x16x32_bf16(af, bfrag[ks], acc, 0, 0, 0);
            }
            // softmax over i (lanes bi=0..7) per row j = wv*16 + kg*4 + rr
            #pragma unroll
            for (int rr = 0; rr < 4; ++rr){
                float d = acc[rr] + qbl;
                float mx = d;
                mx = fmaxf(mx, __shfl_xor(mx, 1));
                mx = fmaxf(mx, __shfl_xor(mx, 2));
                mx = fmaxf(mx, __shfl_xor(mx, 4));
                float e = __expf(d - mx);
                float se = e;
                se += __shfl_xor(se, 1);
                se += __shfl_xor(se, 2);
                se += __shfl_xor(se, 4);
                float p = e/se + EPS_;
                if (bi < 8){
                    ps[(wv*16 + kg*4 + rr)*8 + bi] = f2bf(p);
                    s8loc += p;
                }
            }
        }
        if (ch < 7){
            unsigned short* xw = &xs[(cur ^ 8192) + r*256];
            *(ushort8*)&xw[(og*32 +  0) ^ ssw] = s0;
            *(ushort8*)&xw[(og*32 +  8) ^ ssw] = s1;
            *(ushort8*)&xw[(og*32 + 16) ^ ssw] = s2;
            *(ushort8*)&xw[(og*32 + 24) ^ ssw] = s3;
        }
        __syncthreads();
        // ---- PV: thread (islot, cg) accumulates u over this chunk's 32 rows ----
        #pragma unroll 4
        for (int jj = 0; jj < 32; ++jj){
            float pw = bf2f(ps[jj*8 + islot]);
            ushort8 vv = *(const ushort8*)&xs[cur + jj*256 + ((cg*8) ^ ((jj & 7) << 3))];
            u0[0] += pw*bf2f(vv[0]); u0[1] += pw*bf2f(vv[1]);
            u0[2] += pw*bf2f(vv[2]); u0[3] += pw*bf2f(vv[3]);
            u1[0] += pw*bf2f(vv[4]); u1[1] += pw*bf2f(vv[5]);
            u1[2] += pw*bf2f(vv[6]); u1[3] += pw*bf2f(vv[7]);
        }
        __syncthreads();
    }
    // ---- Spart: reduce s8loc over kg groups (lanes ^16, ^32), combine 2 QK waves ----
    if (wv < 2){
        s8loc += __shfl_xor(s8loc, 16);
        s8loc += __shfl_xor(s8loc, 32);
        if (l < 8) swred[wv][l] = s8loc;
    }
    __syncthreads();
    if (t < 8)
        Spart[((size_t)(b*16 + jb))*8 + t] = swred[0][t] + swred[1][t];
    {
        float* up = Upart + (((size_t)(b*16 + jb))*8 + islot)*256 + cg*8;
        float4 o0; o0.x = u0[0]; o0.y = u0[1]; o0.z = u0[2]; o0.w = u0[3];
        float4 o1; o1.x = u1[0]; o1.y = u1[1]; o1.z = u1[2]; o1.w = u1[3];
        *(float4*)up       = o0;
        *(float4*)(up + 4) = o1;
    }
}

// ---------------- per-iter: slotu1 = Upart reduce + Wv GEMM + GRU n-slice  (grid (B,4), 512) ----------------
__global__ void slotu1_kernel(const float* __restrict__ slots, const float* __restrict__ Spart,
                              const float* __restrict__ Upart, const float* __restrict__ Wv,
                              const float* __restrict__ bv, const float* __restrict__ W_ih,
                              const float* __restrict__ b_ih, const float* __restrict__ W_hh,
                              const float* __restrict__ b_hh, float* __restrict__ slots2){
    __shared__ float us[8][260], sp[8][260], upd[8][260];
    const int t = threadIdx.x, b = blockIdx.x, ng = blockIdx.y;
    const int i = t >> 6, l = t & 63;
    {
        float a0 = 0.f, a1 = 0.f, a2 = 0.f, a3 = 0.f, S = 0.f;
        #pragma unroll
        for (int jbl = 0; jbl < 16; ++jbl){
            float4 u4 = *(const float4*)(Upart + (((size_t)(b*16 + jbl))*8 + i)*256 + l*4);
            a0 += u4.x; a1 += u4.y; a2 += u4.z; a3 += u4.w;
            S += Spart[((size_t)(b*16 + jbl))*8 + i];
        }
        float invS = 1.f / S;
        us[i][l*4+0] = a0*invS; us[i][l*4+1] = a1*invS;
        us[i][l*4+2] = a2*invS; us[i][l*4+3] = a3*invS;
        float4 s4 = *(const float4*)(slots + ((size_t)b*8 + i)*256 + l*4);
        sp[i][l*4+0] = s4.x; sp[i][l*4+1] = s4.y; sp[i][l*4+2] = s4.z; sp[i][l*4+3] = s4.w;
    }
    __syncthreads();
    {   // upd = us @ Wv + bv (full width, redundant across ng blocks), chunked streaming
        const int c4 = l*4;
        float4 acc = *(const float4*)(bv + c4);
        #pragma unroll
        for (int cb = 0; cb < 256; cb += 16){
            float4 w4[16];
            #pragma unroll
            for (int u = 0; u < 16; ++u)
                w4[u] = *(const float4*)(Wv + (size_t)(cb+u)*256 + c4);
            #pragma unroll
            for (int u = 0; u < 16; ++u){
                float uv = us[i][cb+u];
                acc.x += uv*w4[u].x; acc.y += uv*w4[u].y;
                acc.z += uv*w4[u].z; acc.w += uv*w4[u].w;
            }
        }
        *(float4*)&upd[i][c4] = acc;
    }
    __syncthreads();
    {   // GRU for n-slice, 6 streams chunked 8 deep
        const int n = ng*64 + l;
        float xr = b_ih[n], xz = b_ih[256+n], xn = b_ih[512+n];
        float hr = b_hh[n], hz = b_hh[256+n], hn = b_hh[512+n];
        #pragma unroll 2
        for (int cb = 0; cb < 256; cb += 8){
            float wi0[8], wi1[8], wi2[8], wh0[8], wh1[8], wh2[8];
            #pragma unroll
            for (int u = 0; u < 8; ++u){
                const float* wi = W_ih + (size_t)(cb+u)*768 + n;
                const float* wh = W_hh + (size_t)(cb+u)*768 + n;
                wi0[u] = wi[0]; wi1[u] = wi[256]; wi2[u] = wi[512];
                wh0[u] = wh[0]; wh1[u] = wh[256]; wh2[u] = wh[512];
            }
            #pragma unroll
            for (int u = 0; u < 8; ++u){
                float uv = upd[i][cb+u], sv = sp[i][cb+u];
                xr += uv*wi0[u]; xz += uv*wi1[u]; xn += uv*wi2[u];
                hr += sv*wh0[u]; hz += sv*wh1[u]; hn += sv*wh2[u];
            }
        }
        float rv = 1.f/(1.f + __expf(-(xr + hr)));
        float zv = 1.f/(1.f + __expf(-(xz + hz)));
        float nn = tanhf(xn + rv*hn);
        slots2[((size_t)b*8 + i)*256 + n] = (1.f - zv)*nn + zv*sp[i][n];
    }
}

// ---------------- per-iter: slotu2 = LN_ff + FFN1 + FFN2 n-slice  (grid (B,4), 512) ----------------
__global__ void slotu2_kernel(const float* __restrict__ slots2, const float* __restrict__ gf,
                              const float* __restrict__ bf, const float* __restrict__ W1,
                              const float* __restrict__ b1, const float* __restrict__ W2,
                              const float* __restrict__ b2, float* __restrict__ slots,
                              float* __restrict__ dout){
    __shared__ float s0[8][260], pre[8][260], hb[8][260];
    const int t = threadIdx.x, b = blockIdx.x, ng = blockIdx.y;
    const int i = t >> 6, l = t & 63;
    {
        float4 v4 = *(const float4*)(slots2 + ((size_t)b*8 + i)*256 + l*4);
        float sum = v4.x + v4.y + v4.z + v4.w;
        float sq  = v4.x*v4.x + v4.y*v4.y + v4.z*v4.z + v4.w*v4.w;
        #pragma unroll
        for (int m = 1; m < 64; m <<= 1){ sum += __shfl_xor(sum, m); sq += __shfl_xor(sq, m); }
        float mean = sum * (1.f/256.f);
        float rstd = rsqrtf(sq * (1.f/256.f) - mean*mean + 1e-5f);
        float4 g4 = *(const float4*)(gf + l*4);
        float4 b4 = *(const float4*)(bf + l*4);
        s0[i][l*4+0] = v4.x; s0[i][l*4+1] = v4.y; s0[i][l*4+2] = v4.z; s0[i][l*4+3] = v4.w;
        pre[i][l*4+0] = (v4.x - mean)*rstd*g4.x + b4.x;
        pre[i][l*4+1] = (v4.y - mean)*rstd*g4.y + b4.y;
        pre[i][l*4+2] = (v4.z - mean)*rstd*g4.z + b4.z;
        pre[i][l*4+3] = (v4.w - mean)*rstd*g4.w + b4.w;
    }
    __syncthreads();
    {   // h = relu(pre @ W1 + b1) (full width, redundant), chunked streaming
        const int h4 = l*4;
        float4 acc = *(const float4*)(b1 + h4);
        #pragma unroll
        for (int cb = 0; cb < 256; cb += 16){
            float4 w4[16];
            #pragma unroll
            for (int u = 0; u < 16; ++u)
                w4[u] = *(const float4*)(W1 + (size_t)(cb+u)*256 + h4);
            #pragma unroll
            for (int u = 0; u < 16; ++u){
                float pv = pre[i][cb+u];
                acc.x += pv*w4[u].x; acc.y += pv*w4[u].y;
                acc.z += pv*w4[u].z; acc.w += pv*w4[u].w;
            }
        }
        hb[i][h4+0] = fmaxf(acc.x, 0.f); hb[i][h4+1] = fmaxf(acc.y, 0.f);
        hb[i][h4+2] = fmaxf(acc.z, 0.f); hb[i][h4+3] = fmaxf(acc.w, 0.f);
    }
    __syncthreads();
    {   // out = s0 + h @ W2 + b2, n-slice, chunked streaming
        const int n = ng*64 + l;
        float acc = b2[n];
        #pragma unroll
        for (int mb = 0; mb < 256; mb += 64){
            float w[64];
            #pragma unroll
            for (int u = 0; u < 64; ++u) w[u] = W2[(size_t)(mb+u)*256 + n];
            #pragma unroll
            for (int u = 0; u < 64; ++u) acc += hb[i][mb+u]*w[u];
        }
        float val = s0[i][n] + acc;
        size_t off = ((size_t)b*8 + i)*256 + n;
        slots[off] = val;
        dout[off]  = val;
    }
}

extern "C" void kernel_launch(void* const* d_in, const int* in_sizes, int n_in,
                              void* d_out, int out_size, void* d_ws, size_t ws_size,
                              hipStream_t stream){
    const float* inputs = (const float*)d_in[0];
    const float* noise  = (const float*)d_in[1];
    const float* mu     = (const float*)d_in[2];
    const float* lsig   = (const float*)d_in[3];
    const float* g_in   = (const float*)d_in[4];
    const float* b_in   = (const float*)d_in[5];
    const float* g_s    = (const float*)d_in[6];
    const float* b_s    = (const float*)d_in[7];
    const float* g_ff   = (const float*)d_in[8];
    const float* b_ff   = (const float*)d_in[9];
    const float* Wq     = (const float*)d_in[10];
    const float* bq     = (const float*)d_in[11];
    const float* Wk     = (const float*)d_in[12];
    const float* bk     = (const float*)d_in[13];
    const float* Wv     = (const float*)d_in[14];
    const float* bv     = (const float*)d_in[15];
    const float* W_ih   = (const float*)d_in[16];
    const float* b_ih   = (const float*)d_in[17];
    const float* W_hh   = (const float*)d_in[18];
    const float* b_hh   = (const float*)d_in[19];
    const float* W1     = (const float*)d_in[20];
    const float* b1     = (const float*)d_in[21];
    const float* W2     = (const float*)d_in[22];
    const float* b2     = (const float*)d_in[23];

    char* ws = (char*)d_ws;
    unsigned short* XH  = (unsigned short*)(ws);               // 128 MB
    float* Upart        = (float*)(ws + ((size_t)128 << 20));  // 8 MB
    float* Spart        = (float*)(ws + ((size_t)136 << 20));  // 8 KB
    float* qtbuf        = (float*)(ws + ((size_t)137 << 20));  // 512 KB
    float* qbb          = (float*)(ws + ((size_t)138 << 20));  // 2 KB
    float* slots        = (float*)(ws + ((size_t)139 << 20));  // 512 KB
    float* slots2       = (float*)(ws + ((size_t)140 << 20));  // 512 KB
    float* WqkT         = (float*)(ws + ((size_t)141 << 20));  // 256 KB
    float* bqt          = (float*)(ws + ((size_t)142 << 20));  // 1 KB
    float* wqb          = (float*)(ws + ((size_t)143 << 20));  // 1 KB
    float* bqkv         = (float*)(ws + ((size_t)144 << 20));  // 4 B

    prep1_kernel<<<512, 256, 0, stream>>>(mu, lsig, noise, slots);
    prep2_kernel<<<256, 256, 0, stream>>>(Wq, Wk, bq, bk, WqkT, bqt, wqb, bqkv);
    ln_kernel<<<M_/32, 256, 0, stream>>>(inputs, g_in, b_in, XH);
    for (int it = 0; it < ITERS_; ++it){
        slotq_kernel<<<dim3(B_, 4), 512, 0, stream>>>(slots, WqkT, bqt, wqb, bqkv,
                                                      g_s, b_s, qtbuf, qbb);
        attn_kernel<<<dim3(B_, 16), 256, 0, stream>>>(XH, qtbuf, qbb, Spart, Upart);
        slotu1_kernel<<<dim3(B_, 4), 512, 0, stream>>>(slots, Spart, Upart, Wv, bv,
                                                       W_ih, b_ih, W_hh, b_hh, slots2);
        slotu2_kernel<<<dim3(B_, 4), 512, 0, stream>>>(slots2, g_ff, b_ff, W1, b1, W2, b2,
                                                       slots, (float*)d_out);
    }
}

// Round 9
// 530.218 us; speedup vs baseline: 2.3003x; 1.0426x over previous
//
#include <hip/hip_runtime.h>
#include <hip/hip_bf16.h>

#define B_ 64
#define N_ 4096
#define C_ 256
#define K_ 8
#define M_ (B_*N_)
#define ITERS_ 3
#define SCALE_ 0.0625f
#define EPS_ 1e-8f

typedef __attribute__((ext_vector_type(4))) float f32x4;
typedef __attribute__((ext_vector_type(8))) __bf16 bf16x8;
typedef __attribute__((ext_vector_type(8))) unsigned short ushort8;
typedef __attribute__((ext_vector_type(4))) unsigned short ushort4v;

static __device__ __forceinline__ unsigned short f2bf(float f){
    union { float f; unsigned u; } v; v.f = f;
    unsigned r = v.u + 0x7fffu + ((v.u >> 16) & 1u);
    return (unsigned short)(r >> 16);
}
static __device__ __forceinline__ float bf2f(unsigned short h){
    union { unsigned u; float f; } v; v.u = ((unsigned)h) << 16;
    return v.f;
}

// ---------------- prep1: slots init ----------------
__global__ void prep1_kernel(const float* __restrict__ mu, const float* __restrict__ lsig,
                             const float* __restrict__ noise, float* __restrict__ slots){
    int idx = blockIdx.x*256 + threadIdx.x;   // 0..131071
    int c = idx & 255, i = (idx >> 8) & 7;
    slots[idx] = mu[c] + expf(lsig[c])*noise[i*256 + c];
}

// ---------------- prep2: WqkT = Wq@Wk^T, bqt = bq@Wk^T, wqb = Wq@bk, bqk = bq.bk ----------------
__global__ void prep2_kernel(const float* __restrict__ Wq, const float* __restrict__ Wk,
                             const float* __restrict__ bq, const float* __restrict__ bk,
                             float* __restrict__ WqkT, float* __restrict__ bqt,
                             float* __restrict__ wqb, float* __restrict__ bqkv){
    __shared__ float wqrow[256], bkl[256], bql[256];
    __shared__ float red[4], red2[4];
    const int t = threadIdx.x, c = blockIdx.x;
    wqrow[t] = Wq[(size_t)c*256 + t];
    bkl[t] = bk[t];
    bql[t] = bq[t];
    __syncthreads();
    float acc = 0.f, accb = 0.f;
    const float* wkr = Wk + (size_t)t*256;
    #pragma unroll 4
    for (int d = 0; d < 256; d += 4){
        float4 wk4 = *(const float4*)(wkr + d);
        float4 wq4 = *(const float4*)(&wqrow[d]);
        float4 bq4 = *(const float4*)(&bql[d]);
        acc  += wq4.x*wk4.x + wq4.y*wk4.y + wq4.z*wk4.z + wq4.w*wk4.w;
        accb += bq4.x*wk4.x + bq4.y*wk4.y + bq4.z*wk4.z + bq4.w*wk4.w;
    }
    WqkT[(size_t)c*256 + t] = acc;
    if (c == 0) bqt[t] = accb;
    float pw = wqrow[t]*bkl[t];
    float pb = bql[t]*bkl[t];
    #pragma unroll
    for (int m = 1; m < 64; m <<= 1){ pw += __shfl_xor(pw, m); pb += __shfl_xor(pb, m); }
    if ((t & 63) == 0){ red[t >> 6] = pw; red2[t >> 6] = pb; }
    __syncthreads();
    if (t == 0){
        wqb[c] = red[0] + red[1] + red[2] + red[3];
        if (c == 0) bqkv[0] = red2[0] + red2[1] + red2[2] + red2[3];
    }
}

// ---------------- x -> x_hat bf16; layout XH[jt][og(0..7)][rloc(0..255)][32c] ----------------
__global__ void ln_kernel(const float* __restrict__ x, const float* __restrict__ g,
                          const float* __restrict__ bta, unsigned short* __restrict__ XH){
    const int t = threadIdx.x;
    const int row = blockIdx.x*32 + (t >> 3), sl = t & 7;
    const float* xr = x + (size_t)row*C_ + sl*32;
    float v[32];
    #pragma unroll
    for (int q = 0; q < 8; ++q) *(float4*)&v[q*4] = *(const float4*)(xr + q*4);
    float sum = 0.f, sq = 0.f;
    #pragma unroll
    for (int e = 0; e < 32; ++e){ sum += v[e]; sq += v[e]*v[e]; }
    #pragma unroll
    for (int m = 1; m < 8; m <<= 1){ sum += __shfl_xor(sum, m); sq += __shfl_xor(sq, m); }
    float mean = sum * (1.f/256.f);
    float rstd = rsqrtf(sq * (1.f/256.f) - mean*mean + 1e-5f);
    const int jt = row >> 8, rloc = row & 255;
    unsigned short* dst = XH + (((size_t)jt*8 + sl)*256 + rloc)*32;
    #pragma unroll
    for (int u = 0; u < 4; ++u){
        float4 g0 = *(const float4*)(g + sl*32 + u*8);
        float4 g1 = *(const float4*)(g + sl*32 + u*8 + 4);
        float4 b0 = *(const float4*)(bta + sl*32 + u*8);
        float4 b1 = *(const float4*)(bta + sl*32 + u*8 + 4);
        const float* gp0 = (const float*)&g0; const float* gp1 = (const float*)&g1;
        const float* bp0 = (const float*)&b0; const float* bp1 = (const float*)&b1;
        ushort8 pk;
        #pragma unroll
        for (int e = 0; e < 4; ++e){
            pk[e]   = f2bf((v[u*8+e]   - mean)*rstd*gp0[e] + bp0[e]);
            pk[4+e] = f2bf((v[u*8+4+e] - mean)*rstd*gp1[e] + bp1[e]);
        }
        *(ushort8*)(dst + u*8) = pk;
    }
}

// ---------------- per-iter: slotq = LN_s + q~ = SCALE*(sn@Wqk + bqt), qb  (grid (B,4), 512) ----------------
__global__ void slotq_kernel(const float* __restrict__ slots, const float* __restrict__ WqkT,
                             const float* __restrict__ bqt, const float* __restrict__ wqb,
                             const float* __restrict__ bqkv, const float* __restrict__ gs,
                             const float* __restrict__ bs, float* __restrict__ qtbuf,
                             float* __restrict__ qbb){
    __shared__ float sn[8][260];
    const int t = threadIdx.x, b = blockIdx.x, cgb = blockIdx.y;
    const int i = t >> 6, l = t & 63;
    {
        float4 v4 = *(const float4*)(slots + ((size_t)b*8 + i)*256 + l*4);
        float sum = v4.x + v4.y + v4.z + v4.w;
        float sq  = v4.x*v4.x + v4.y*v4.y + v4.z*v4.z + v4.w*v4.w;
        #pragma unroll
        for (int m = 1; m < 64; m <<= 1){ sum += __shfl_xor(sum, m); sq += __shfl_xor(sq, m); }
        float mean = sum * (1.f/256.f);
        float rstd = rsqrtf(sq * (1.f/256.f) - mean*mean + 1e-5f);
        float4 g4 = *(const float4*)(gs + l*4);
        float4 b4 = *(const float4*)(bs + l*4);
        float n0 = (v4.x - mean)*rstd*g4.x + b4.x;
        float n1 = (v4.y - mean)*rstd*g4.y + b4.y;
        float n2 = (v4.z - mean)*rstd*g4.z + b4.z;
        float n3 = (v4.w - mean)*rstd*g4.w + b4.w;
        sn[i][l*4+0] = n0; sn[i][l*4+1] = n1; sn[i][l*4+2] = n2; sn[i][l*4+3] = n3;
        if (cgb == 0){
            float4 w4 = *(const float4*)(wqb + l*4);
            float pb = n0*w4.x + n1*w4.y + n2*w4.z + n3*w4.w;
            #pragma unroll
            for (int m = 1; m < 64; m <<= 1) pb += __shfl_xor(pb, m);
            if (l == 0) qbb[(size_t)b*8 + i] = SCALE_*(pb + bqkv[0]);
        }
    }
    __syncthreads();
    const int col = cgb*64 + l;
    float acc = bqt[col];
    #pragma unroll
    for (int cb = 0; cb < 256; cb += 64){
        float w[64];
        #pragma unroll
        for (int u = 0; u < 64; ++u) w[u] = WqkT[(size_t)(cb+u)*256 + col];
        #pragma unroll
        for (int u = 0; u < 64; ++u) acc += sn[i][cb+u]*w[u];
    }
    qtbuf[((size_t)b*8 + i)*256 + col] = SCALE_*acc;
}

// ---------------- per-iter: fused attn — MFMA QK + in-frag softmax + MFMA PV  (grid (B,16), 256) ----------------
// Swizzle: row j stores c-slot o at slot (o ^ SW(j)), SW(j) = (j&7) ^ (((j>>3)&3)<<1).
__global__ void attn_kernel(const unsigned short* __restrict__ XH, const float* __restrict__ qt,
                            const float* __restrict__ qb, float* __restrict__ Spart,
                            float* __restrict__ Upart){
    __shared__ __align__(16) unsigned short xs[2*8192];   // 2 x 32rows x 256c, swizzled (32 KB)
    __shared__ __align__(16) unsigned short pst[16*40];   // p^T bf16: [i][j], rows padded to 40
    __shared__ float swred[2][8];
    const int t = threadIdx.x, b = blockIdx.x, jb = blockIdx.y;
    const unsigned short* XB = XH + (size_t)(b*16 + jb)*65536;
    const int wv = t >> 6, l = t & 63;
    const int bi = l & 15, kg = l >> 4;

    // B-fragments: q~ held in registers (QK waves 0-1 only)
    bf16x8 bfrag[8];
    float qbl = 0.f;
    {
        const ushort8 zz = (ushort8){0,0,0,0,0,0,0,0};
        #pragma unroll
        for (int ks = 0; ks < 8; ++ks) bfrag[ks] = __builtin_bit_cast(bf16x8, zz);
        if (wv < 2 && bi < 8){
            #pragma unroll
            for (int ks = 0; ks < 8; ++ks){
                const float* qp = qt + ((size_t)b*8 + bi)*256 + ks*32 + kg*8;
                float4 qa = *(const float4*)qp;
                float4 qc = *(const float4*)(qp + 4);
                ushort8 pk;
                pk[0]=f2bf(qa.x); pk[1]=f2bf(qa.y); pk[2]=f2bf(qa.z); pk[3]=f2bf(qa.w);
                pk[4]=f2bf(qc.x); pk[5]=f2bf(qc.y); pk[6]=f2bf(qc.z); pk[7]=f2bf(qc.w);
                bfrag[ks] = __builtin_bit_cast(bf16x8, pk);
            }
            qbl = qb[(size_t)b*8 + bi];
        }
    }

    // stage chunk 0
    const int og = t >> 5, r = t & 31;
    const int swr = (r & 7) ^ (((r >> 3) & 3) << 1);
    ushort8 s0, s1, s2, s3;
    {
        const unsigned short* g0 = XB + ((size_t)og*256 + r)*32;
        s0 = *(const ushort8*)(g0);      s1 = *(const ushort8*)(g0 + 8);
        s2 = *(const ushort8*)(g0 + 16); s3 = *(const ushort8*)(g0 + 24);
    }
    {
        unsigned short* xw = &xs[r*256];
        *(ushort8*)&xw[((og*4 + 0) ^ swr)*8] = s0;
        *(ushort8*)&xw[((og*4 + 1) ^ swr)*8] = s1;
        *(ushort8*)&xw[((og*4 + 2) ^ swr)*8] = s2;
        *(ushort8*)&xw[((og*4 + 3) ^ swr)*8] = s3;
    }
    __syncthreads();

    f32x4 acc[4];
    #pragma unroll
    for (int n = 0; n < 4; ++n) acc[n] = (f32x4){0.f,0.f,0.f,0.f};
    float s8loc = 0.f;
    // PV per-lane constants: c = ct*16 + bi; column-read base terms
    const int pv_lo = bi & 7;                 // c&7 (short offset inside 16B slot)
    const int pv_sl = (bi >> 3) ^ (kg << 1);  // (c>>3 low bit) ^ g<<1, XOR'd with ct*2 and e

    for (int ch = 0; ch < 8; ++ch){
        const int cur = (ch & 1) << 13;
        if (ch < 7){
            const unsigned short* g1 = XB + ((size_t)og*256 + (ch+1)*32 + r)*32;
            s0 = *(const ushort8*)(g1);      s1 = *(const ushort8*)(g1 + 8);
            s2 = *(const ushort8*)(g1 + 16); s3 = *(const ushort8*)(g1 + 24);
        }
        // ---- QK via MFMA: waves 0-1 compute 16-row tiles; softmax in-fragment ----
        if (wv < 2){
            f32x4 qacc = (f32x4){0.f,0.f,0.f,0.f};
            const int rowL = wv*16 + bi;
            const int swrow = (rowL & 7) ^ (((rowL >> 3) & 3) << 1);
            const unsigned short* xrow = &xs[cur + rowL*256];
            #pragma unroll
            for (int ks = 0; ks < 8; ++ks){
                int chn = (ks*4 + kg) ^ swrow;
                bf16x8 af = *(const bf16x8*)&xrow[chn*8];
                qacc = __builtin_amdgcn_mfma_f32_16x16x32_bf16(af, bfrag[ks], qacc, 0, 0, 0);
            }
            ushort4v p4;
            #pragma unroll
            for (int rr = 0; rr < 4; ++rr){
                float d = qacc[rr] + qbl;
                float mx = d;
                mx = fmaxf(mx, __shfl_xor(mx, 1));
                mx = fmaxf(mx, __shfl_xor(mx, 2));
                mx = fmaxf(mx, __shfl_xor(mx, 4));
                float e = __expf(d - mx);
                float se = e;
                se += __shfl_xor(se, 1);
                se += __shfl_xor(se, 2);
                se += __shfl_xor(se, 4);
                float p = e/se + EPS_;
                p4[rr] = f2bf(p);
                if (bi < 8) s8loc += p;
            }
            if (bi < 8)
                *(ushort4v*)&pst[bi*40 + wv*16 + kg*4] = p4;   // pst[i][j]
        }
        if (ch < 7){
            unsigned short* xw = &xs[(cur ^ 8192) + r*256];
            *(ushort8*)&xw[((og*4 + 0) ^ swr)*8] = s0;
            *(ushort8*)&xw[((og*4 + 1) ^ swr)*8] = s1;
            *(ushort8*)&xw[((og*4 + 2) ^ swr)*8] = s2;
            *(ushort8*)&xw[((og*4 + 3) ^ swr)*8] = s3;
        }
        __syncthreads();
        // ---- PV via MFMA: A = P (from pst), B = X column fragments; wave wv owns ct = wv*4+n ----
        {
            ushort8 pa = *(const ushort8*)&pst[bi*40 + kg*8];    // P[i=bi][j=8kg+e]
            #pragma unroll
            for (int n = 0; n < 4; ++n){
                const int ct2 = (wv*4 + n) << 1;
                ushort8 xv;
                #pragma unroll
                for (int e = 0; e < 8; ++e){
                    int slot = (ct2 ^ pv_sl ^ e) ^ ((e & 4) ? 0 : 0); // slot index (5 bits)
                    xv[e] = xs[cur + kg*2048 + e*256 + (slot << 3) + pv_lo];
                }
                acc[n] = __builtin_amdgcn_mfma_f32_16x16x32_bf16(
                    __builtin_bit_cast(bf16x8, pa), __builtin_bit_cast(bf16x8, xv), acc[n], 0, 0, 0);
            }
        }
        __syncthreads();
    }
    // ---- Spart ----
    if (wv < 2){
        s8loc += __shfl_xor(s8loc, 16);
        s8loc += __shfl_xor(s8loc, 32);
        if (l < 8) swred[wv][l] = s8loc;
    }
    __syncthreads();
    if (t < 8)
        Spart[((size_t)(b*16 + jb))*8 + t] = swred[0][t] + swred[1][t];
    // ---- Upart from D-fragments: lane holds i = kg*4+r (kg<2 valid), c = ct*16+bi ----
    if (kg < 2){
        #pragma unroll
        for (int n = 0; n < 4; ++n){
            const int ct = wv*4 + n;
            #pragma unroll
            for (int r2 = 0; r2 < 4; ++r2){
                int i = kg*4 + r2;
                Upart[(((size_t)(b*16 + jb))*8 + i)*256 + ct*16 + bi] = acc[n][r2];
            }
        }
    }
}

// ---------------- per-iter: slotu1 = Upart reduce + Wv GEMM + GRU n-slice  (grid (B,4), 512) ----------------
__global__ void slotu1_kernel(const float* __restrict__ slots, const float* __restrict__ Spart,
                              const float* __restrict__ Upart, const float* __restrict__ Wv,
                              const float* __restrict__ bv, const float* __restrict__ W_ih,
                              const float* __restrict__ b_ih, const float* __restrict__ W_hh,
                              const float* __restrict__ b_hh, float* __restrict__ slots2){
    __shared__ float us[8][260], sp[8][260], upd[8][260];
    const int t = threadIdx.x, b = blockIdx.x, ng = blockIdx.y;
    const int i = t >> 6, l = t & 63;
    {
        float a0 = 0.f, a1 = 0.f, a2 = 0.f, a3 = 0.f, S = 0.f;
        #pragma unroll
        for (int jbl = 0; jbl < 16; ++jbl){
            float4 u4 = *(const float4*)(Upart + (((size_t)(b*16 + jbl))*8 + i)*256 + l*4);
            a0 += u4.x; a1 += u4.y; a2 += u4.z; a3 += u4.w;
            S += Spart[((size_t)(b*16 + jbl))*8 + i];
        }
        float invS = 1.f / S;
        us[i][l*4+0] = a0*invS; us[i][l*4+1] = a1*invS;
        us[i][l*4+2] = a2*invS; us[i][l*4+3] = a3*invS;
        float4 s4 = *(const float4*)(slots + ((size_t)b*8 + i)*256 + l*4);
        sp[i][l*4+0] = s4.x; sp[i][l*4+1] = s4.y; sp[i][l*4+2] = s4.z; sp[i][l*4+3] = s4.w;
    }
    __syncthreads();
    {   // upd = us @ Wv + bv (full width, redundant across ng blocks), chunked streaming
        const int c4 = l*4;
        float4 acc = *(const float4*)(bv + c4);
        #pragma unroll
        for (int cb = 0; cb < 256; cb += 16){
            float4 w4[16];
            #pragma unroll
            for (int u = 0; u < 16; ++u)
                w4[u] = *(const float4*)(Wv + (size_t)(cb+u)*256 + c4);
            #pragma unroll
            for (int u = 0; u < 16; ++u){
                float uv = us[i][cb+u];
                acc.x += uv*w4[u].x; acc.y += uv*w4[u].y;
                acc.z += uv*w4[u].z; acc.w += uv*w4[u].w;
            }
        }
        *(float4*)&upd[i][c4] = acc;
    }
    __syncthreads();
    {   // GRU for n-slice, 6 streams chunked 8 deep
        const int n = ng*64 + l;
        float xr = b_ih[n], xz = b_ih[256+n], xn = b_ih[512+n];
        float hr = b_hh[n], hz = b_hh[256+n], hn = b_hh[512+n];
        #pragma unroll 2
        for (int cb = 0; cb < 256; cb += 8){
            float wi0[8], wi1[8], wi2[8], wh0[8], wh1[8], wh2[8];
            #pragma unroll
            for (int u = 0; u < 8; ++u){
                const float* wi = W_ih + (size_t)(cb+u)*768 + n;
                const float* wh = W_hh + (size_t)(cb+u)*768 + n;
                wi0[u] = wi[0]; wi1[u] = wi[256]; wi2[u] = wi[512];
                wh0[u] = wh[0]; wh1[u] = wh[256]; wh2[u] = wh[512];
            }
            #pragma unroll
            for (int u = 0; u < 8; ++u){
                float uv = upd[i][cb+u], sv = sp[i][cb+u];
                xr += uv*wi0[u]; xz += uv*wi1[u]; xn += uv*wi2[u];
                hr += sv*wh0[u]; hz += sv*wh1[u]; hn += sv*wh2[u];
            }
        }
        float rv = 1.f/(1.f + __expf(-(xr + hr)));
        float zv = 1.f/(1.f + __expf(-(xz + hz)));
        float nn = tanhf(xn + rv*hn);
        slots2[((size_t)b*8 + i)*256 + n] = (1.f - zv)*nn + zv*sp[i][n];
    }
}

// ---------------- per-iter: slotu2 = LN_ff + FFN1 + FFN2 n-slice  (grid (B,4), 512) ----------------
__global__ void slotu2_kernel(const float* __restrict__ slots2, const float* __restrict__ gf,
                              const float* __restrict__ bf, const float* __restrict__ W1,
                              const float* __restrict__ b1, const float* __restrict__ W2,
                              const float* __restrict__ b2, float* __restrict__ slots,
                              float* __restrict__ dout){
    __shared__ float s0[8][260], pre[8][260], hb[8][260];
    const int t = threadIdx.x, b = blockIdx.x, ng = blockIdx.y;
    const int i = t >> 6, l = t & 63;
    {
        float4 v4 = *(const float4*)(slots2 + ((size_t)b*8 + i)*256 + l*4);
        float sum = v4.x + v4.y + v4.z + v4.w;
        float sq  = v4.x*v4.x + v4.y*v4.y + v4.z*v4.z + v4.w*v4.w;
        #pragma unroll
        for (int m = 1; m < 64; m <<= 1){ sum += __shfl_xor(sum, m); sq += __shfl_xor(sq, m); }
        float mean = sum * (1.f/256.f);
        float rstd = rsqrtf(sq * (1.f/256.f) - mean*mean + 1e-5f);
        float4 g4 = *(const float4*)(gf + l*4);
        float4 b4 = *(const float4*)(bf + l*4);
        s0[i][l*4+0] = v4.x; s0[i][l*4+1] = v4.y; s0[i][l*4+2] = v4.z; s0[i][l*4+3] = v4.w;
        pre[i][l*4+0] = (v4.x - mean)*rstd*g4.x + b4.x;
        pre[i][l*4+1] = (v4.y - mean)*rstd*g4.y + b4.y;
        pre[i][l*4+2] = (v4.z - mean)*rstd*g4.z + b4.z;
        pre[i][l*4+3] = (v4.w - mean)*rstd*g4.w + b4.w;
    }
    __syncthreads();
    {   // h = relu(pre @ W1 + b1) (full width, redundant), chunked streaming
        const int h4 = l*4;
        float4 acc = *(const float4*)(b1 + h4);
        #pragma unroll
        for (int cb = 0; cb < 256; cb += 16){
            float4 w4[16];
            #pragma unroll
            for (int u = 0; u < 16; ++u)
                w4[u] = *(const float4*)(W1 + (size_t)(cb+u)*256 + h4);
            #pragma unroll
            for (int u = 0; u < 16; ++u){
                float pv = pre[i][cb+u];
                acc.x += pv*w4[u].x; acc.y += pv*w4[u].y;
                acc.z += pv*w4[u].z; acc.w += pv*w4[u].w;
            }
        }
        hb[i][h4+0] = fmaxf(acc.x, 0.f); hb[i][h4+1] = fmaxf(acc.y, 0.f);
        hb[i][h4+2] = fmaxf(acc.z, 0.f); hb[i][h4+3] = fmaxf(acc.w, 0.f);
    }
    __syncthreads();
    {   // out = s0 + h @ W2 + b2, n-slice, chunked streaming
        const int n = ng*64 + l;
        float acc = b2[n];
        #pragma unroll
        for (int mb = 0; mb < 256; mb += 64){
            float w[64];
            #pragma unroll
            for (int u = 0; u < 64; ++u) w[u] = W2[(size_t)(mb+u)*256 + n];
            #pragma unroll
            for (int u = 0; u < 64; ++u) acc += hb[i][mb+u]*w[u];
        }
        float val = s0[i][n] + acc;
        size_t off = ((size_t)b*8 + i)*256 + n;
        slots[off] = val;
        dout[off]  = val;
    }
}

extern "C" void kernel_launch(void* const* d_in, const int* in_sizes, int n_in,
                              void* d_out, int out_size, void* d_ws, size_t ws_size,
                              hipStream_t stream){
    const float* inputs = (const float*)d_in[0];
    const float* noise  = (const float*)d_in[1];
    const float* mu     = (const float*)d_in[2];
    const float* lsig   = (const float*)d_in[3];
    const float* g_in   = (const float*)d_in[4];
    const float* b_in   = (const float*)d_in[5];
    const float* g_s    = (const float*)d_in[6];
    const float* b_s    = (const float*)d_in[7];
    const float* g_ff   = (const float*)d_in[8];
    const float* b_ff   = (const float*)d_in[9];
    const float* Wq     = (const float*)d_in[10];
    const float* bq     = (const float*)d_in[11];
    const float* Wk     = (const float*)d_in[12];
    const float* bk     = (const float*)d_in[13];
    const float* Wv     = (const float*)d_in[14];
    const float* bv     = (const float*)d_in[15];
    const float* W_ih   = (const float*)d_in[16];
    const float* b_ih   = (const float*)d_in[17];
    const float* W_hh   = (const float*)d_in[18];
    const float* b_hh   = (const float*)d_in[19];
    const float* W1     = (const float*)d_in[20];
    const float* b1     = (const float*)d_in[21];
    const float* W2     = (const float*)d_in[22];
    const float* b2     = (const float*)d_in[23];

    char* ws = (char*)d_ws;
    unsigned short* XH  = (unsigned short*)(ws);               // 128 MB
    float* Upart        = (float*)(ws + ((size_t)128 << 20));  // 8 MB
    float* Spart        = (float*)(ws + ((size_t)136 << 20));  // 8 KB
    float* qtbuf        = (float*)(ws + ((size_t)137 << 20));  // 512 KB
    float* qbb          = (float*)(ws + ((size_t)138 << 20));  // 2 KB
    float* slots        = (float*)(ws + ((size_t)139 << 20));  // 512 KB
    float* slots2       = (float*)(ws + ((size_t)140 << 20));  // 512 KB
    float* WqkT         = (float*)(ws + ((size_t)141 << 20));  // 256 KB
    float* bqt          = (float*)(ws + ((size_t)142 << 20));  // 1 KB
    float* wqb          = (float*)(ws + ((size_t)143 << 20));  // 1 KB
    float* bqkv         = (float*)(ws + ((size_t)144 << 20));  // 4 B

    prep1_kernel<<<512, 256, 0, stream>>>(mu, lsig, noise, slots);
    prep2_kernel<<<256, 256, 0, stream>>>(Wq, Wk, bq, bk, WqkT, bqt, wqb, bqkv);
    ln_kernel<<<M_/32, 256, 0, stream>>>(inputs, g_in, b_in, XH);
    for (int it = 0; it < ITERS_; ++it){
        slotq_kernel<<<dim3(B_, 4), 512, 0, stream>>>(slots, WqkT, bqt, wqb, bqkv,
                                                      g_s, b_s, qtbuf, qbb);
        attn_kernel<<<dim3(B_, 16), 256, 0, stream>>>(XH, qtbuf, qbb, Spart, Upart);
        slotu1_kernel<<<dim3(B_, 4), 512, 0, stream>>>(slots, Spart, Upart, Wv, bv,
                                                       W_ih, b_ih, W_hh, b_hh, slots2);
        slotu2_kernel<<<dim3(B_, 4), 512, 0, stream>>>(slots2, g_ff, b_ff, W1, b1, W2, b2,
                                                       slots, (float*)d_out);
    }
}

// Round 10
// 513.073 us; speedup vs baseline: 2.3772x; 1.0334x over previous
//
#include <hip/hip_runtime.h>
#include <hip/hip_bf16.h>

#define B_ 64
#define N_ 4096
#define C_ 256
#define K_ 8
#define M_ (B_*N_)
#define ITERS_ 3
#define SCALE_ 0.0625f
#define EPS_ 1e-8f

typedef __attribute__((ext_vector_type(4))) float f32x4;
typedef __attribute__((ext_vector_type(8))) __bf16 bf16x8;
typedef __attribute__((ext_vector_type(8))) unsigned short ushort8;
typedef __attribute__((ext_vector_type(4))) unsigned short ushort4v;

static __device__ __forceinline__ unsigned short f2bf(float f){
    union { float f; unsigned u; } v; v.f = f;
    unsigned r = v.u + 0x7fffu + ((v.u >> 16) & 1u);
    return (unsigned short)(r >> 16);
}
static __device__ __forceinline__ float bf2f(unsigned short h){
    union { unsigned u; float f; } v; v.u = ((unsigned)h) << 16;
    return v.f;
}

// ---------------- prep1: slots init ----------------
__global__ void prep1_kernel(const float* __restrict__ mu, const float* __restrict__ lsig,
                             const float* __restrict__ noise, float* __restrict__ slots){
    int idx = blockIdx.x*256 + threadIdx.x;   // 0..131071
    int c = idx & 255, i = (idx >> 8) & 7;
    slots[idx] = mu[c] + expf(lsig[c])*noise[i*256 + c];
}

// ---------------- prep2: WqkT = Wq@Wk^T, bqt = bq@Wk^T, wqb = Wq@bk, bqk = bq.bk ----------------
__global__ void prep2_kernel(const float* __restrict__ Wq, const float* __restrict__ Wk,
                             const float* __restrict__ bq, const float* __restrict__ bk,
                             float* __restrict__ WqkT, float* __restrict__ bqt,
                             float* __restrict__ wqb, float* __restrict__ bqkv){
    __shared__ float wqrow[256], bkl[256], bql[256];
    __shared__ float red[4], red2[4];
    const int t = threadIdx.x, c = blockIdx.x;
    wqrow[t] = Wq[(size_t)c*256 + t];
    bkl[t] = bk[t];
    bql[t] = bq[t];
    __syncthreads();
    float acc = 0.f, accb = 0.f;
    const float* wkr = Wk + (size_t)t*256;
    #pragma unroll 4
    for (int d = 0; d < 256; d += 4){
        float4 wk4 = *(const float4*)(wkr + d);
        float4 wq4 = *(const float4*)(&wqrow[d]);
        float4 bq4 = *(const float4*)(&bql[d]);
        acc  += wq4.x*wk4.x + wq4.y*wk4.y + wq4.z*wk4.z + wq4.w*wk4.w;
        accb += bq4.x*wk4.x + bq4.y*wk4.y + bq4.z*wk4.z + bq4.w*wk4.w;
    }
    WqkT[(size_t)c*256 + t] = acc;
    if (c == 0) bqt[t] = accb;
    float pw = wqrow[t]*bkl[t];
    float pb = bql[t]*bkl[t];
    #pragma unroll
    for (int m = 1; m < 64; m <<= 1){ pw += __shfl_xor(pw, m); pb += __shfl_xor(pb, m); }
    if ((t & 63) == 0){ red[t >> 6] = pw; red2[t >> 6] = pb; }
    __syncthreads();
    if (t == 0){
        wqb[c] = red[0] + red[1] + red[2] + red[3];
        if (c == 0) bqkv[0] = red2[0] + red2[1] + red2[2] + red2[3];
    }
}

// ---------------- x -> x_hat bf16; layout XH[jt][og(0..7)][rloc(0..255)][32c] ----------------
__global__ void ln_kernel(const float* __restrict__ x, const float* __restrict__ g,
                          const float* __restrict__ bta, unsigned short* __restrict__ XH){
    const int t = threadIdx.x;
    const int row = blockIdx.x*32 + (t >> 3), sl = t & 7;
    const float* xr = x + (size_t)row*C_ + sl*32;
    float v[32];
    #pragma unroll
    for (int q = 0; q < 8; ++q) *(float4*)&v[q*4] = *(const float4*)(xr + q*4);
    float sum = 0.f, sq = 0.f;
    #pragma unroll
    for (int e = 0; e < 32; ++e){ sum += v[e]; sq += v[e]*v[e]; }
    #pragma unroll
    for (int m = 1; m < 8; m <<= 1){ sum += __shfl_xor(sum, m); sq += __shfl_xor(sq, m); }
    float mean = sum * (1.f/256.f);
    float rstd = rsqrtf(sq * (1.f/256.f) - mean*mean + 1e-5f);
    const int jt = row >> 8, rloc = row & 255;
    unsigned short* dst = XH + (((size_t)jt*8 + sl)*256 + rloc)*32;
    #pragma unroll
    for (int u = 0; u < 4; ++u){
        float4 g0 = *(const float4*)(g + sl*32 + u*8);
        float4 g1 = *(const float4*)(g + sl*32 + u*8 + 4);
        float4 b0 = *(const float4*)(bta + sl*32 + u*8);
        float4 b1 = *(const float4*)(bta + sl*32 + u*8 + 4);
        const float* gp0 = (const float*)&g0; const float* gp1 = (const float*)&g1;
        const float* bp0 = (const float*)&b0; const float* bp1 = (const float*)&b1;
        ushort8 pk;
        #pragma unroll
        for (int e = 0; e < 4; ++e){
            pk[e]   = f2bf((v[u*8+e]   - mean)*rstd*gp0[e] + bp0[e]);
            pk[4+e] = f2bf((v[u*8+4+e] - mean)*rstd*gp1[e] + bp1[e]);
        }
        *(ushort8*)(dst + u*8) = pk;
    }
}

// ---------------- per-iter: slotq = LN_s + q~ = SCALE*(sn@Wqk + bqt), qb  (grid (B,4), 512) ----------------
__global__ void slotq_kernel(const float* __restrict__ slots, const float* __restrict__ WqkT,
                             const float* __restrict__ bqt, const float* __restrict__ wqb,
                             const float* __restrict__ bqkv, const float* __restrict__ gs,
                             const float* __restrict__ bs, float* __restrict__ qtbuf,
                             float* __restrict__ qbb){
    __shared__ float sn[8][260];
    const int t = threadIdx.x, b = blockIdx.x, cgb = blockIdx.y;
    const int i = t >> 6, l = t & 63;
    {
        float4 v4 = *(const float4*)(slots + ((size_t)b*8 + i)*256 + l*4);
        float sum = v4.x + v4.y + v4.z + v4.w;
        float sq  = v4.x*v4.x + v4.y*v4.y + v4.z*v4.z + v4.w*v4.w;
        #pragma unroll
        for (int m = 1; m < 64; m <<= 1){ sum += __shfl_xor(sum, m); sq += __shfl_xor(sq, m); }
        float mean = sum * (1.f/256.f);
        float rstd = rsqrtf(sq * (1.f/256.f) - mean*mean + 1e-5f);
        float4 g4 = *(const float4*)(gs + l*4);
        float4 b4 = *(const float4*)(bs + l*4);
        float n0 = (v4.x - mean)*rstd*g4.x + b4.x;
        float n1 = (v4.y - mean)*rstd*g4.y + b4.y;
        float n2 = (v4.z - mean)*rstd*g4.z + b4.z;
        float n3 = (v4.w - mean)*rstd*g4.w + b4.w;
        sn[i][l*4+0] = n0; sn[i][l*4+1] = n1; sn[i][l*4+2] = n2; sn[i][l*4+3] = n3;
        if (cgb == 0){
            float4 w4 = *(const float4*)(wqb + l*4);
            float pb = n0*w4.x + n1*w4.y + n2*w4.z + n3*w4.w;
            #pragma unroll
            for (int m = 1; m < 64; m <<= 1) pb += __shfl_xor(pb, m);
            if (l == 0) qbb[(size_t)b*8 + i] = SCALE_*(pb + bqkv[0]);
        }
    }
    __syncthreads();
    const int col = cgb*64 + l;
    float acc = bqt[col];
    #pragma unroll
    for (int cb = 0; cb < 256; cb += 64){
        float w[64];
        #pragma unroll
        for (int u = 0; u < 64; ++u) w[u] = WqkT[(size_t)(cb+u)*256 + col];
        #pragma unroll
        for (int u = 0; u < 64; ++u) acc += sn[i][cb+u]*w[u];
    }
    qtbuf[((size_t)b*8 + i)*256 + col] = SCALE_*acc;
}

// ---------------- per-iter: fused attn v3 — wave-specialized pipeline, raw barriers ----------------
// grid (B,16), 512 threads = 8 waves. Waves 0-1: QK MFMA + softmax; 2-3: staging; 4-7: PV MFMA.
// LDS: 4-deep ring of 32row x 256c swizzled chunks (64KB) + 2-deep pst.
// Swizzle: row j stores c-slot o at (o ^ SW(j)), SW(j) = (j&7) ^ (((j>>3)&3)<<1).
__global__ __launch_bounds__(512)
void attn_kernel(const unsigned short* __restrict__ XH, const float* __restrict__ qt,
                 const float* __restrict__ qb, float* __restrict__ Spart,
                 float* __restrict__ Upart){
    __shared__ __align__(16) unsigned short xs[4*8192];
    __shared__ __align__(16) unsigned short pst[2][16*40];
    __shared__ float swred[2][8];
    const int t = threadIdx.x, b = blockIdx.x, jb = blockIdx.y;
    const unsigned short* XB = XH + (size_t)(b*16 + jb)*65536;
    const int wv = t >> 6, l = t & 63;
    const int bi = l & 15, kg = l >> 4;
    const bool isQK = (wv < 2), isST = (wv == 2 || wv == 3), isPV = (wv >= 4);

    // --- QK setup: q~ B-fragments in registers ---
    bf16x8 bfrag[8];
    float qbl = 0.f;
    {
        const ushort8 zz = (ushort8){0,0,0,0,0,0,0,0};
        #pragma unroll
        for (int ks = 0; ks < 8; ++ks) bfrag[ks] = __builtin_bit_cast(bf16x8, zz);
        if (isQK && bi < 8){
            #pragma unroll
            for (int ks = 0; ks < 8; ++ks){
                const float* qp = qt + ((size_t)b*8 + bi)*256 + ks*32 + kg*8;
                float4 qa = *(const float4*)qp;
                float4 qc = *(const float4*)(qp + 4);
                ushort8 pk;
                pk[0]=f2bf(qa.x); pk[1]=f2bf(qa.y); pk[2]=f2bf(qa.z); pk[3]=f2bf(qa.w);
                pk[4]=f2bf(qc.x); pk[5]=f2bf(qc.y); pk[6]=f2bf(qc.z); pk[7]=f2bf(qc.w);
                bfrag[ks] = __builtin_bit_cast(bf16x8, pk);
            }
            qbl = qb[(size_t)b*8 + bi];
        }
    }
    // --- staging setup (waves 2-3): lane covers row r, og pair (og0, og0+1), 4x16B each ---
    const int rstg = (wv & 1)*16 + bi;            // wave2: rows 0-15, wave3: 16-31
    const int og0 = (l >> 4) * 2;
    const int swrr = (rstg & 7) ^ (((rstg >> 3) & 3) << 1);
    ushort8 S[8];
    // --- PV setup (waves 4-7): c-tiles ct = (wv-4)*4 + n ---
    f32x4 acc[4];
    #pragma unroll
    for (int n = 0; n < 4; ++n) acc[n] = (f32x4){0.f,0.f,0.f,0.f};
    const int pv_lo = bi & 7;
    const int pv_sl = (bi >> 3) ^ (kg << 1);
    float s8loc = 0.f;

#define STG_LOAD(ch) { \
    _Pragma("unroll") for (int o2 = 0; o2 < 2; ++o2){ \
        const unsigned short* gp = XB + ((size_t)(og0+o2)*256 + (ch)*32 + rstg)*32; \
        _Pragma("unroll") for (int u = 0; u < 4; ++u) S[o2*4+u] = *(const ushort8*)(gp + u*8); } }
#define STG_WRITE(ch) { \
    unsigned short* xw = &xs[((ch)&3)*8192 + rstg*256]; \
    _Pragma("unroll") for (int o2 = 0; o2 < 2; ++o2){ \
        _Pragma("unroll") for (int u = 0; u < 4; ++u) \
            *(ushort8*)&xw[((((og0+o2)*4 + u) ^ swrr)*8)] = S[o2*4+u]; } }
#define BARR() { asm volatile("s_waitcnt lgkmcnt(0)" ::: "memory"); __builtin_amdgcn_s_barrier(); }

    // prologue: fill buf0, buf1; loads for ch1 in S entering loop... (ch0 written immediately)
    if (isST){
        STG_LOAD(0); STG_WRITE(0);
        STG_LOAD(1);
    }
    BARR();   // buf0 visible (ch1 regs in flight / written at p=0)

    #pragma unroll
    for (int p = 0; p < 8; ++p){
        // PV(p-1): waves 4-7
        if (isPV && p >= 1){
            const int cur = ((p-1) & 3) * 8192;
            ushort8 pa = *(const ushort8*)&pst[(p-1) & 1][bi*40 + kg*8];
            #pragma unroll
            for (int n = 0; n < 4; ++n){
                const int ct2 = ((wv - 4)*4 + n) << 1;
                ushort8 xv;
                #pragma unroll
                for (int e = 0; e < 8; ++e){
                    int slot = ct2 ^ pv_sl ^ e;
                    xv[e] = xs[cur + kg*2048 + e*256 + (slot << 3) + pv_lo];
                }
                acc[n] = __builtin_amdgcn_mfma_f32_16x16x32_bf16(
                    __builtin_bit_cast(bf16x8, pa), __builtin_bit_cast(bf16x8, xv), acc[n], 0, 0, 0);
            }
        }
        // QK(p): waves 0-1
        if (isQK){
            const int cur = (p & 3) * 8192;
            f32x4 qacc = (f32x4){0.f,0.f,0.f,0.f};
            const int rowL = wv*16 + bi;
            const int swrow = (rowL & 7) ^ (((rowL >> 3) & 3) << 1);
            const unsigned short* xrow = &xs[cur + rowL*256];
            #pragma unroll
            for (int ks = 0; ks < 8; ++ks){
                int chn = (ks*4 + kg) ^ swrow;
                bf16x8 af = *(const bf16x8*)&xrow[chn*8];
                qacc = __builtin_amdgcn_mfma_f32_16x16x32_bf16(af, bfrag[ks], qacc, 0, 0, 0);
            }
            ushort4v p4;
            #pragma unroll
            for (int rr = 0; rr < 4; ++rr){
                float d = qacc[rr] + qbl;
                float mx = d;
                mx = fmaxf(mx, __shfl_xor(mx, 1));
                mx = fmaxf(mx, __shfl_xor(mx, 2));
                mx = fmaxf(mx, __shfl_xor(mx, 4));
                float e = __expf(d - mx);
                float se = e;
                se += __shfl_xor(se, 1);
                se += __shfl_xor(se, 2);
                se += __shfl_xor(se, 4);
                float pv = e/se + EPS_;
                p4[rr] = f2bf(pv);
                if (bi < 8) s8loc += pv;
            }
            if (bi < 8)
                *(ushort4v*)&pst[p & 1][bi*40 + wv*16 + kg*4] = p4;
        }
        // staging: write buf p+1 (loads issued last iter), issue loads for p+2
        if (isST){
            if (p + 1 <= 7) STG_WRITE(p + 1);
            if (p + 2 <= 7) STG_LOAD(p + 2);
        }
        BARR();
    }
    // epilogue: PV(7)
    if (isPV){
        const int cur = (7 & 3) * 8192;
        ushort8 pa = *(const ushort8*)&pst[7 & 1][bi*40 + kg*8];
        #pragma unroll
        for (int n = 0; n < 4; ++n){
            const int ct2 = ((wv - 4)*4 + n) << 1;
            ushort8 xv;
            #pragma unroll
            for (int e = 0; e < 8; ++e){
                int slot = ct2 ^ pv_sl ^ e;
                xv[e] = xs[cur + kg*2048 + e*256 + (slot << 3) + pv_lo];
            }
            acc[n] = __builtin_amdgcn_mfma_f32_16x16x32_bf16(
                __builtin_bit_cast(bf16x8, pa), __builtin_bit_cast(bf16x8, xv), acc[n], 0, 0, 0);
        }
    }
    // Spart from QK waves
    if (isQK){
        float s = s8loc;
        s += __shfl_xor(s, 16);
        s += __shfl_xor(s, 32);
        if (l < 8) swred[wv][l] = s;
    }
    BARR();
    if (t < 8)
        Spart[((size_t)(b*16 + jb))*8 + t] = swred[0][t] + swred[1][t];
    // Upart from PV D-fragments: lane i = kg*4+r2 (kg<2), c = ct*16+bi
    if (isPV && kg < 2){
        #pragma unroll
        for (int n = 0; n < 4; ++n){
            const int ct = (wv - 4)*4 + n;
            #pragma unroll
            for (int r2 = 0; r2 < 4; ++r2){
                int i = kg*4 + r2;
                Upart[(((size_t)(b*16 + jb))*8 + i)*256 + ct*16 + bi] = acc[n][r2];
            }
        }
    }
#undef STG_LOAD
#undef STG_WRITE
#undef BARR
}

// ---------------- per-iter: slotu1 = Upart reduce + Wv GEMM + GRU n-slice  (grid (B,4), 512) ----------------
__global__ void slotu1_kernel(const float* __restrict__ slots, const float* __restrict__ Spart,
                              const float* __restrict__ Upart, const float* __restrict__ Wv,
                              const float* __restrict__ bv, const float* __restrict__ W_ih,
                              const float* __restrict__ b_ih, const float* __restrict__ W_hh,
                              const float* __restrict__ b_hh, float* __restrict__ slots2){
    __shared__ float us[8][260], sp[8][260], upd[8][260];
    const int t = threadIdx.x, b = blockIdx.x, ng = blockIdx.y;
    const int i = t >> 6, l = t & 63;
    {
        float a0 = 0.f, a1 = 0.f, a2 = 0.f, a3 = 0.f, S = 0.f;
        #pragma unroll
        for (int jbl = 0; jbl < 16; ++jbl){
            float4 u4 = *(const float4*)(Upart + (((size_t)(b*16 + jbl))*8 + i)*256 + l*4);
            a0 += u4.x; a1 += u4.y; a2 += u4.z; a3 += u4.w;
            S += Spart[((size_t)(b*16 + jbl))*8 + i];
        }
        float invS = 1.f / S;
        us[i][l*4+0] = a0*invS; us[i][l*4+1] = a1*invS;
        us[i][l*4+2] = a2*invS; us[i][l*4+3] = a3*invS;
        float4 s4 = *(const float4*)(slots + ((size_t)b*8 + i)*256 + l*4);
        sp[i][l*4+0] = s4.x; sp[i][l*4+1] = s4.y; sp[i][l*4+2] = s4.z; sp[i][l*4+3] = s4.w;
    }
    __syncthreads();
    {
        const int c4 = l*4;
        float4 acc = *(const float4*)(bv + c4);
        #pragma unroll
        for (int cb = 0; cb < 256; cb += 16){
            float4 w4[16];
            #pragma unroll
            for (int u = 0; u < 16; ++u)
                w4[u] = *(const float4*)(Wv + (size_t)(cb+u)*256 + c4);
            #pragma unroll
            for (int u = 0; u < 16; ++u){
                float uv = us[i][cb+u];
                acc.x += uv*w4[u].x; acc.y += uv*w4[u].y;
                acc.z += uv*w4[u].z; acc.w += uv*w4[u].w;
            }
        }
        *(float4*)&upd[i][c4] = acc;
    }
    __syncthreads();
    {
        const int n = ng*64 + l;
        float xr = b_ih[n], xz = b_ih[256+n], xn = b_ih[512+n];
        float hr = b_hh[n], hz = b_hh[256+n], hn = b_hh[512+n];
        #pragma unroll 2
        for (int cb = 0; cb < 256; cb += 8){
            float wi0[8], wi1[8], wi2[8], wh0[8], wh1[8], wh2[8];
            #pragma unroll
            for (int u = 0; u < 8; ++u){
                const float* wi = W_ih + (size_t)(cb+u)*768 + n;
                const float* wh = W_hh + (size_t)(cb+u)*768 + n;
                wi0[u] = wi[0]; wi1[u] = wi[256]; wi2[u] = wi[512];
                wh0[u] = wh[0]; wh1[u] = wh[256]; wh2[u] = wh[512];
            }
            #pragma unroll
            for (int u = 0; u < 8; ++u){
                float uv = upd[i][cb+u], sv = sp[i][cb+u];
                xr += uv*wi0[u]; xz += uv*wi1[u]; xn += uv*wi2[u];
                hr += sv*wh0[u]; hz += sv*wh1[u]; hn += sv*wh2[u];
            }
        }
        float rv = 1.f/(1.f + __expf(-(xr + hr)));
        float zv = 1.f/(1.f + __expf(-(xz + hz)));
        float nn = tanhf(xn + rv*hn);
        slots2[((size_t)b*8 + i)*256 + n] = (1.f - zv)*nn + zv*sp[i][n];
    }
}

// ---------------- per-iter: slotu2 = LN_ff + FFN1 + FFN2 n-slice  (grid (B,4), 512) ----------------
__global__ void slotu2_kernel(const float* __restrict__ slots2, const float* __restrict__ gf,
                              const float* __restrict__ bf, const float* __restrict__ W1,
                              const float* __restrict__ b1, const float* __restrict__ W2,
                              const float* __restrict__ b2, float* __restrict__ slots,
                              float* __restrict__ dout){
    __shared__ float s0[8][260], pre[8][260], hb[8][260];
    const int t = threadIdx.x, b = blockIdx.x, ng = blockIdx.y;
    const int i = t >> 6, l = t & 63;
    {
        float4 v4 = *(const float4*)(slots2 + ((size_t)b*8 + i)*256 + l*4);
        float sum = v4.x + v4.y + v4.z + v4.w;
        float sq  = v4.x*v4.x + v4.y*v4.y + v4.z*v4.z + v4.w*v4.w;
        #pragma unroll
        for (int m = 1; m < 64; m <<= 1){ sum += __shfl_xor(sum, m); sq += __shfl_xor(sq, m); }
        float mean = sum * (1.f/256.f);
        float rstd = rsqrtf(sq * (1.f/256.f) - mean*mean + 1e-5f);
        float4 g4 = *(const float4*)(gf + l*4);
        float4 b4 = *(const float4*)(bf + l*4);
        s0[i][l*4+0] = v4.x; s0[i][l*4+1] = v4.y; s0[i][l*4+2] = v4.z; s0[i][l*4+3] = v4.w;
        pre[i][l*4+0] = (v4.x - mean)*rstd*g4.x + b4.x;
        pre[i][l*4+1] = (v4.y - mean)*rstd*g4.y + b4.y;
        pre[i][l*4+2] = (v4.z - mean)*rstd*g4.z + b4.z;
        pre[i][l*4+3] = (v4.w - mean)*rstd*g4.w + b4.w;
    }
    __syncthreads();
    {
        const int h4 = l*4;
        float4 acc = *(const float4*)(b1 + h4);
        #pragma unroll
        for (int cb = 0; cb < 256; cb += 16){
            float4 w4[16];
            #pragma unroll
            for (int u = 0; u < 16; ++u)
                w4[u] = *(const float4*)(W1 + (size_t)(cb+u)*256 + h4);
            #pragma unroll
            for (int u = 0; u < 16; ++u){
                float pv = pre[i][cb+u];
                acc.x += pv*w4[u].x; acc.y += pv*w4[u].y;
                acc.z += pv*w4[u].z; acc.w += pv*w4[u].w;
            }
        }
        hb[i][h4+0] = fmaxf(acc.x, 0.f); hb[i][h4+1] = fmaxf(acc.y, 0.f);
        hb[i][h4+2] = fmaxf(acc.z, 0.f); hb[i][h4+3] = fmaxf(acc.w, 0.f);
    }
    __syncthreads();
    {
        const int n = ng*64 + l;
        float acc = b2[n];
        #pragma unroll
        for (int mb = 0; mb < 256; mb += 64){
            float w[64];
            #pragma unroll
            for (int u = 0; u < 64; ++u) w[u] = W2[(size_t)(mb+u)*256 + n];
            #pragma unroll
            for (int u = 0; u < 64; ++u) acc += hb[i][mb+u]*w[u];
        }
        float val = s0[i][n] + acc;
        size_t off = ((size_t)b*8 + i)*256 + n;
        slots[off] = val;
        dout[off]  = val;
    }
}

extern "C" void kernel_launch(void* const* d_in, const int* in_sizes, int n_in,
                              void* d_out, int out_size, void* d_ws, size_t ws_size,
                              hipStream_t stream){
    const float* inputs = (const float*)d_in[0];
    const float* noise  = (const float*)d_in[1];
    const float* mu     = (const float*)d_in[2];
    const float* lsig   = (const float*)d_in[3];
    const float* g_in   = (const float*)d_in[4];
    const float* b_in   = (const float*)d_in[5];
    const float* g_s    = (const float*)d_in[6];
    const float* b_s    = (const float*)d_in[7];
    const float* g_ff   = (const float*)d_in[8];
    const float* b_ff   = (const float*)d_in[9];
    const float* Wq     = (const float*)d_in[10];
    const float* bq     = (const float*)d_in[11];
    const float* Wk     = (const float*)d_in[12];
    const float* bk     = (const float*)d_in[13];
    const float* Wv     = (const float*)d_in[14];
    const float* bv     = (const float*)d_in[15];
    const float* W_ih   = (const float*)d_in[16];
    const float* b_ih   = (const float*)d_in[17];
    const float* W_hh   = (const float*)d_in[18];
    const float* b_hh   = (const float*)d_in[19];
    const float* W1     = (const float*)d_in[20];
    const float* b1     = (const float*)d_in[21];
    const float* W2     = (const float*)d_in[22];
    const float* b2     = (const float*)d_in[23];

    char* ws = (char*)d_ws;
    unsigned short* XH  = (unsigned short*)(ws);               // 128 MB
    float* Upart        = (float*)(ws + ((size_t)128 << 20));  // 8 MB
    float* Spart        = (float*)(ws + ((size_t)136 << 20));  // 8 KB
    float* qtbuf        = (float*)(ws + ((size_t)137 << 20));  // 512 KB
    float* qbb          = (float*)(ws + ((size_t)138 << 20));  // 2 KB
    float* slots        = (float*)(ws + ((size_t)139 << 20));  // 512 KB
    float* slots2       = (float*)(ws + ((size_t)140 << 20));  // 512 KB
    float* WqkT         = (float*)(ws + ((size_t)141 << 20));  // 256 KB
    float* bqt          = (float*)(ws + ((size_t)142 << 20));  // 1 KB
    float* wqb          = (float*)(ws + ((size_t)143 << 20));  // 1 KB
    float* bqkv         = (float*)(ws + ((size_t)144 << 20));  // 4 B

    prep1_kernel<<<512, 256, 0, stream>>>(mu, lsig, noise, slots);
    prep2_kernel<<<256, 256, 0, stream>>>(Wq, Wk, bq, bk, WqkT, bqt, wqb, bqkv);
    ln_kernel<<<M_/32, 256, 0, stream>>>(inputs, g_in, b_in, XH);
    for (int it = 0; it < ITERS_; ++it){
        slotq_kernel<<<dim3(B_, 4), 512, 0, stream>>>(slots, WqkT, bqt, wqb, bqkv,
                                                      g_s, b_s, qtbuf, qbb);
        attn_kernel<<<dim3(B_, 16), 512, 0, stream>>>(XH, qtbuf, qbb, Spart, Upart);
        slotu1_kernel<<<dim3(B_, 4), 512, 0, stream>>>(slots, Spart, Upart, Wv, bv,
                                                       W_ih, b_ih, W_hh, b_hh, slots2);
        slotu2_kernel<<<dim3(B_, 4), 512, 0, stream>>>(slots2, g_ff, b_ff, W1, b1, W2, b2,
                                                       slots, (float*)d_out);
    }
}

// Round 11
// 459.369 us; speedup vs baseline: 2.6551x; 1.1169x over previous
//
#include <hip/hip_runtime.h>
#include <hip/hip_bf16.h>

#define B_ 64
#define N_ 4096
#define C_ 256
#define K_ 8
#define M_ (B_*N_)
#define ITERS_ 3
#define SCALE_ 0.0625f
#define EPS_ 1e-8f

typedef __attribute__((ext_vector_type(4))) float f32x4;
typedef __attribute__((ext_vector_type(8))) __bf16 bf16x8;
typedef __attribute__((ext_vector_type(8))) unsigned short ushort8;
typedef __attribute__((ext_vector_type(4))) unsigned short ushort4v;

static __device__ __forceinline__ unsigned short f2bf(float f){
    union { float f; unsigned u; } v; v.f = f;
    unsigned r = v.u + 0x7fffu + ((v.u >> 16) & 1u);
    return (unsigned short)(r >> 16);
}
static __device__ __forceinline__ float bf2f(unsigned short h){
    union { unsigned u; float f; } v; v.u = ((unsigned)h) << 16;
    return v.f;
}

// ---------------- prep1: slots init ----------------
__global__ void prep1_kernel(const float* __restrict__ mu, const float* __restrict__ lsig,
                             const float* __restrict__ noise, float* __restrict__ slots){
    int idx = blockIdx.x*256 + threadIdx.x;   // 0..131071
    int c = idx & 255, i = (idx >> 8) & 7;
    slots[idx] = mu[c] + expf(lsig[c])*noise[i*256 + c];
}

// ---------------- prep2: WqkT = Wq@Wk^T, bqt = bq@Wk^T, wqb = Wq@bk, bqk = bq.bk ----------------
__global__ void prep2_kernel(const float* __restrict__ Wq, const float* __restrict__ Wk,
                             const float* __restrict__ bq, const float* __restrict__ bk,
                             float* __restrict__ WqkT, float* __restrict__ bqt,
                             float* __restrict__ wqb, float* __restrict__ bqkv){
    __shared__ float wqrow[256], bkl[256], bql[256];
    __shared__ float red[4], red2[4];
    const int t = threadIdx.x, c = blockIdx.x;
    wqrow[t] = Wq[(size_t)c*256 + t];
    bkl[t] = bk[t];
    bql[t] = bq[t];
    __syncthreads();
    float acc = 0.f, accb = 0.f;
    const float* wkr = Wk + (size_t)t*256;
    #pragma unroll 4
    for (int d = 0; d < 256; d += 4){
        float4 wk4 = *(const float4*)(wkr + d);
        float4 wq4 = *(const float4*)(&wqrow[d]);
        float4 bq4 = *(const float4*)(&bql[d]);
        acc  += wq4.x*wk4.x + wq4.y*wk4.y + wq4.z*wk4.z + wq4.w*wk4.w;
        accb += bq4.x*wk4.x + bq4.y*wk4.y + bq4.z*wk4.z + bq4.w*wk4.w;
    }
    WqkT[(size_t)c*256 + t] = acc;
    if (c == 0) bqt[t] = accb;
    float pw = wqrow[t]*bkl[t];
    float pb = bql[t]*bkl[t];
    #pragma unroll
    for (int m = 1; m < 64; m <<= 1){ pw += __shfl_xor(pw, m); pb += __shfl_xor(pb, m); }
    if ((t & 63) == 0){ red[t >> 6] = pw; red2[t >> 6] = pb; }
    __syncthreads();
    if (t == 0){
        wqb[c] = red[0] + red[1] + red[2] + red[3];
        if (c == 0) bqkv[0] = red2[0] + red2[1] + red2[2] + red2[3];
    }
}

// ---------------- x -> x_hat bf16; layout XH[jt][og(0..7)][rloc(0..255)][32c] ----------------
// Lane map: 8 lanes per row, lane s owns 16B pieces at s*16B + q*128B -> every read instr
// is 8 x 128B contiguous; every store instr is 512B contiguous per og region.
__global__ void ln_kernel(const float* __restrict__ x, const float* __restrict__ g,
                          const float* __restrict__ bta, unsigned short* __restrict__ XH){
    const int t = threadIdx.x;
    const int row = blockIdx.x*32 + (t >> 3), s = t & 7;
    const float* xr = x + (size_t)row*C_;
    float v[32];
    #pragma unroll
    for (int q = 0; q < 8; ++q)
        *(float4*)&v[q*4] = *(const float4*)(xr + s*4 + q*32);
    float sum = 0.f, sq = 0.f;
    #pragma unroll
    for (int e = 0; e < 32; ++e){ sum += v[e]; sq += v[e]*v[e]; }
    #pragma unroll
    for (int m = 1; m < 8; m <<= 1){ sum += __shfl_xor(sum, m); sq += __shfl_xor(sq, m); }
    float mean = sum * (1.f/256.f);
    float rstd = rsqrtf(sq * (1.f/256.f) - mean*mean + 1e-5f);
    const int jt = row >> 8, rloc = row & 255;
    #pragma unroll
    for (int q = 0; q < 8; ++q){
        float4 g4 = *(const float4*)(g + q*32 + s*4);
        float4 b4 = *(const float4*)(bta + q*32 + s*4);
        ushort4v pk;
        pk[0] = f2bf((v[q*4+0] - mean)*rstd*g4.x + b4.x);
        pk[1] = f2bf((v[q*4+1] - mean)*rstd*g4.y + b4.y);
        pk[2] = f2bf((v[q*4+2] - mean)*rstd*g4.z + b4.z);
        pk[3] = f2bf((v[q*4+3] - mean)*rstd*g4.w + b4.w);
        *(ushort4v*)(XH + (((size_t)jt*8 + q)*256 + rloc)*32 + s*4) = pk;
    }
}

// ---------------- per-iter: slotq = LN_s + q~ = SCALE*(sn@Wqk + bqt), qb  (grid (B,4), 512) ----------------
__global__ void slotq_kernel(const float* __restrict__ slots, const float* __restrict__ WqkT,
                             const float* __restrict__ bqt, const float* __restrict__ wqb,
                             const float* __restrict__ bqkv, const float* __restrict__ gs,
                             const float* __restrict__ bs, float* __restrict__ qtbuf,
                             float* __restrict__ qbb){
    __shared__ float sn[8][260];
    const int t = threadIdx.x, b = blockIdx.x, cgb = blockIdx.y;
    const int i = t >> 6, l = t & 63;
    {
        float4 v4 = *(const float4*)(slots + ((size_t)b*8 + i)*256 + l*4);
        float sum = v4.x + v4.y + v4.z + v4.w;
        float sq  = v4.x*v4.x + v4.y*v4.y + v4.z*v4.z + v4.w*v4.w;
        #pragma unroll
        for (int m = 1; m < 64; m <<= 1){ sum += __shfl_xor(sum, m); sq += __shfl_xor(sq, m); }
        float mean = sum * (1.f/256.f);
        float rstd = rsqrtf(sq * (1.f/256.f) - mean*mean + 1e-5f);
        float4 g4 = *(const float4*)(gs + l*4);
        float4 b4 = *(const float4*)(bs + l*4);
        float n0 = (v4.x - mean)*rstd*g4.x + b4.x;
        float n1 = (v4.y - mean)*rstd*g4.y + b4.y;
        float n2 = (v4.z - mean)*rstd*g4.z + b4.z;
        float n3 = (v4.w - mean)*rstd*g4.w + b4.w;
        sn[i][l*4+0] = n0; sn[i][l*4+1] = n1; sn[i][l*4+2] = n2; sn[i][l*4+3] = n3;
        if (cgb == 0){
            float4 w4 = *(const float4*)(wqb + l*4);
            float pb = n0*w4.x + n1*w4.y + n2*w4.z + n3*w4.w;
            #pragma unroll
            for (int m = 1; m < 64; m <<= 1) pb += __shfl_xor(pb, m);
            if (l == 0) qbb[(size_t)b*8 + i] = SCALE_*(pb + bqkv[0]);
        }
    }
    __syncthreads();
    const int col = cgb*64 + l;
    float acc = bqt[col];
    #pragma unroll
    for (int cb = 0; cb < 256; cb += 64){
        float w[64];
        #pragma unroll
        for (int u = 0; u < 64; ++u) w[u] = WqkT[(size_t)(cb+u)*256 + col];
        #pragma unroll
        for (int u = 0; u < 64; ++u) acc += sn[i][cb+u]*w[u];
    }
    qtbuf[((size_t)b*8 + i)*256 + col] = SCALE_*acc;
}

// ---------------- per-iter: fused attn v3 — wave-specialized pipeline, raw barriers ----------------
// grid (B,16), 512 threads = 8 waves. Waves 0-1: QK MFMA + softmax; 2-3: staging; 4-7: PV MFMA.
// LDS: 4-deep ring of 32row x 256c swizzled chunks (64KB) + 2-deep pst.
// Swizzle: row j stores c-slot o at (o ^ SW(j)), SW(j) = (j&7) ^ (((j>>3)&3)<<1).
// Staging lane map: lane = r16*4 + u4 -> every global load instr covers 1KB contiguous.
__global__ __launch_bounds__(512)
void attn_kernel(const unsigned short* __restrict__ XH, const float* __restrict__ qt,
                 const float* __restrict__ qb, float* __restrict__ Spart,
                 float* __restrict__ Upart){
    __shared__ __align__(16) unsigned short xs[4*8192];
    __shared__ __align__(16) unsigned short pst[2][16*40];
    __shared__ float swred[2][8];
    const int t = threadIdx.x, b = blockIdx.x, jb = blockIdx.y;
    const unsigned short* XB = XH + (size_t)(b*16 + jb)*65536;
    const int wv = t >> 6, l = t & 63;
    const int bi = l & 15, kg = l >> 4;
    const bool isQK = (wv < 2), isST = (wv == 2 || wv == 3), isPV = (wv >= 4);

    // --- QK setup: q~ B-fragments in registers ---
    bf16x8 bfrag[8];
    float qbl = 0.f;
    {
        const ushort8 zz = (ushort8){0,0,0,0,0,0,0,0};
        #pragma unroll
        for (int ks = 0; ks < 8; ++ks) bfrag[ks] = __builtin_bit_cast(bf16x8, zz);
        if (isQK && bi < 8){
            #pragma unroll
            for (int ks = 0; ks < 8; ++ks){
                const float* qp = qt + ((size_t)b*8 + bi)*256 + ks*32 + kg*8;
                float4 qa = *(const float4*)qp;
                float4 qc = *(const float4*)(qp + 4);
                ushort8 pk;
                pk[0]=f2bf(qa.x); pk[1]=f2bf(qa.y); pk[2]=f2bf(qa.z); pk[3]=f2bf(qa.w);
                pk[4]=f2bf(qc.x); pk[5]=f2bf(qc.y); pk[6]=f2bf(qc.z); pk[7]=f2bf(qc.w);
                bfrag[ks] = __builtin_bit_cast(bf16x8, pk);
            }
            qbl = qb[(size_t)b*8 + bi];
        }
    }
    // --- staging setup (waves 2-3): lane (r16 = l>>2, u4 = l&3); rows (wv&1)*16 + r16 ---
    const int rstg = (wv & 1)*16 + (l >> 2);
    const int u4 = l & 3;
    const int swrr = (rstg & 7) ^ (((rstg >> 3) & 3) << 1);
    ushort8 S[8];
    // --- PV setup (waves 4-7): c-tiles ct = (wv-4)*4 + n ---
    f32x4 acc[4];
    #pragma unroll
    for (int n = 0; n < 4; ++n) acc[n] = (f32x4){0.f,0.f,0.f,0.f};
    const int pv_lo = bi & 7;
    const int pv_sl = (bi >> 3) ^ (kg << 1);
    float s8loc = 0.f;

#define STG_LOAD(ch) { \
    _Pragma("unroll") for (int og = 0; og < 8; ++og) \
        S[og] = *(const ushort8*)(XB + ((size_t)og*256 + (ch)*32 + rstg)*32 + u4*8); }
#define STG_WRITE(ch) { \
    unsigned short* xw = &xs[((ch)&3)*8192 + rstg*256]; \
    _Pragma("unroll") for (int og = 0; og < 8; ++og) \
        *(ushort8*)&xw[(((og*4 + u4) ^ swrr)*8)] = S[og]; }
#define BARR() { asm volatile("s_waitcnt lgkmcnt(0)" ::: "memory"); __builtin_amdgcn_s_barrier(); }

    // prologue: fill buf0; loads for ch1 in S entering loop
    if (isST){
        STG_LOAD(0); STG_WRITE(0);
        STG_LOAD(1);
    }
    BARR();   // buf0 visible

    #pragma unroll
    for (int p = 0; p < 8; ++p){
        // PV(p-1): waves 4-7
        if (isPV && p >= 1){
            const int cur = ((p-1) & 3) * 8192;
            ushort8 pa = *(const ushort8*)&pst[(p-1) & 1][bi*40 + kg*8];
            #pragma unroll
            for (int n = 0; n < 4; ++n){
                const int ct2 = ((wv - 4)*4 + n) << 1;
                ushort8 xv;
                #pragma unroll
                for (int e = 0; e < 8; ++e){
                    int slot = ct2 ^ pv_sl ^ e;
                    xv[e] = xs[cur + kg*2048 + e*256 + (slot << 3) + pv_lo];
                }
                acc[n] = __builtin_amdgcn_mfma_f32_16x16x32_bf16(
                    __builtin_bit_cast(bf16x8, pa), __builtin_bit_cast(bf16x8, xv), acc[n], 0, 0, 0);
            }
        }
        // QK(p): waves 0-1
        if (isQK){
            const int cur = (p & 3) * 8192;
            f32x4 qacc = (f32x4){0.f,0.f,0.f,0.f};
            const int rowL = wv*16 + bi;
            const int swrow = (rowL & 7) ^ (((rowL >> 3) & 3) << 1);
            const unsigned short* xrow = &xs[cur + rowL*256];
            #pragma unroll
            for (int ks = 0; ks < 8; ++ks){
                int chn = (ks*4 + kg) ^ swrow;
                bf16x8 af = *(const bf16x8*)&xrow[chn*8];
                qacc = __builtin_amdgcn_mfma_f32_16x16x32_bf16(af, bfrag[ks], qacc, 0, 0, 0);
            }
            ushort4v p4;
            #pragma unroll
            for (int rr = 0; rr < 4; ++rr){
                float d = qacc[rr] + qbl;
                float mx = d;
                mx = fmaxf(mx, __shfl_xor(mx, 1));
                mx = fmaxf(mx, __shfl_xor(mx, 2));
                mx = fmaxf(mx, __shfl_xor(mx, 4));
                float e = __expf(d - mx);
                float se = e;
                se += __shfl_xor(se, 1);
                se += __shfl_xor(se, 2);
                se += __shfl_xor(se, 4);
                float pv = e/se + EPS_;
                p4[rr] = f2bf(pv);
                if (bi < 8) s8loc += pv;
            }
            if (bi < 8)
                *(ushort4v*)&pst[p & 1][bi*40 + wv*16 + kg*4] = p4;
        }
        // staging: write buf p+1 (loads issued last iter), issue loads for p+2
        if (isST){
            if (p + 1 <= 7) STG_WRITE(p + 1);
            if (p + 2 <= 7) STG_LOAD(p + 2);
        }
        BARR();
    }
    // epilogue: PV(7)
    if (isPV){
        const int cur = (7 & 3) * 8192;
        ushort8 pa = *(const ushort8*)&pst[7 & 1][bi*40 + kg*8];
        #pragma unroll
        for (int n = 0; n < 4; ++n){
            const int ct2 = ((wv - 4)*4 + n) << 1;
            ushort8 xv;
            #pragma unroll
            for (int e = 0; e < 8; ++e){
                int slot = ct2 ^ pv_sl ^ e;
                xv[e] = xs[cur + kg*2048 + e*256 + (slot << 3) + pv_lo];
            }
            acc[n] = __builtin_amdgcn_mfma_f32_16x16x32_bf16(
                __builtin_bit_cast(bf16x8, pa), __builtin_bit_cast(bf16x8, xv), acc[n], 0, 0, 0);
        }
    }
    // Spart from QK waves
    if (isQK){
        float s = s8loc;
        s += __shfl_xor(s, 16);
        s += __shfl_xor(s, 32);
        if (l < 8) swred[wv][l] = s;
    }
    BARR();
    if (t < 8)
        Spart[((size_t)(b*16 + jb))*8 + t] = swred[0][t] + swred[1][t];
    // Upart from PV D-fragments: lane i = kg*4+r2 (kg<2), c = ct*16+bi
    if (isPV && kg < 2){
        #pragma unroll
        for (int n = 0; n < 4; ++n){
            const int ct = (wv - 4)*4 + n;
            #pragma unroll
            for (int r2 = 0; r2 < 4; ++r2){
                int i = kg*4 + r2;
                Upart[(((size_t)(b*16 + jb))*8 + i)*256 + ct*16 + bi] = acc[n][r2];
            }
        }
    }
#undef STG_LOAD
#undef STG_WRITE
#undef BARR
}

// ---------------- per-iter: slotu1 = Upart reduce + Wv GEMM + GRU n-slice  (grid (B,4), 512) ----------------
__global__ void slotu1_kernel(const float* __restrict__ slots, const float* __restrict__ Spart,
                              const float* __restrict__ Upart, const float* __restrict__ Wv,
                              const float* __restrict__ bv, const float* __restrict__ W_ih,
                              const float* __restrict__ b_ih, const float* __restrict__ W_hh,
                              const float* __restrict__ b_hh, float* __restrict__ slots2){
    __shared__ float us[8][260], sp[8][260], upd[8][260];
    const int t = threadIdx.x, b = blockIdx.x, ng = blockIdx.y;
    const int i = t >> 6, l = t & 63;
    {
        float a0 = 0.f, a1 = 0.f, a2 = 0.f, a3 = 0.f, S = 0.f;
        #pragma unroll
        for (int jbl = 0; jbl < 16; ++jbl){
            float4 u4 = *(const float4*)(Upart + (((size_t)(b*16 + jbl))*8 + i)*256 + l*4);
            a0 += u4.x; a1 += u4.y; a2 += u4.z; a3 += u4.w;
            S += Spart[((size_t)(b*16 + jbl))*8 + i];
        }
        float invS = 1.f / S;
        us[i][l*4+0] = a0*invS; us[i][l*4+1] = a1*invS;
        us[i][l*4+2] = a2*invS; us[i][l*4+3] = a3*invS;
        float4 s4 = *(const float4*)(slots + ((size_t)b*8 + i)*256 + l*4);
        sp[i][l*4+0] = s4.x; sp[i][l*4+1] = s4.y; sp[i][l*4+2] = s4.z; sp[i][l*4+3] = s4.w;
    }
    __syncthreads();
    {
        const int c4 = l*4;
        float4 acc = *(const float4*)(bv + c4);
        #pragma unroll
        for (int cb = 0; cb < 256; cb += 16){
            float4 w4[16];
            #pragma unroll
            for (int u = 0; u < 16; ++u)
                w4[u] = *(const float4*)(Wv + (size_t)(cb+u)*256 + c4);
            #pragma unroll
            for (int u = 0; u < 16; ++u){
                float uv = us[i][cb+u];
                acc.x += uv*w4[u].x; acc.y += uv*w4[u].y;
                acc.z += uv*w4[u].z; acc.w += uv*w4[u].w;
            }
        }
        *(float4*)&upd[i][c4] = acc;
    }
    __syncthreads();
    {
        const int n = ng*64 + l;
        float xr = b_ih[n], xz = b_ih[256+n], xn = b_ih[512+n];
        float hr = b_hh[n], hz = b_hh[256+n], hn = b_hh[512+n];
        #pragma unroll 2
        for (int cb = 0; cb < 256; cb += 8){
            float wi0[8], wi1[8], wi2[8], wh0[8], wh1[8], wh2[8];
            #pragma unroll
            for (int u = 0; u < 8; ++u){
                const float* wi = W_ih + (size_t)(cb+u)*768 + n;
                const float* wh = W_hh + (size_t)(cb+u)*768 + n;
                wi0[u] = wi[0]; wi1[u] = wi[256]; wi2[u] = wi[512];
                wh0[u] = wh[0]; wh1[u] = wh[256]; wh2[u] = wh[512];
            }
            #pragma unroll
            for (int u = 0; u < 8; ++u){
                float uv = upd[i][cb+u], sv = sp[i][cb+u];
                xr += uv*wi0[u]; xz += uv*wi1[u]; xn += uv*wi2[u];
                hr += sv*wh0[u]; hz += sv*wh1[u]; hn += sv*wh2[u];
            }
        }
        float rv = 1.f/(1.f + __expf(-(xr + hr)));
        float zv = 1.f/(1.f + __expf(-(xz + hz)));
        float nn = tanhf(xn + rv*hn);
        slots2[((size_t)b*8 + i)*256 + n] = (1.f - zv)*nn + zv*sp[i][n];
    }
}

// ---------------- per-iter: slotu2 = LN_ff + FFN1 + FFN2 n-slice  (grid (B,4), 512) ----------------
__global__ void slotu2_kernel(const float* __restrict__ slots2, const float* __restrict__ gf,
                              const float* __restrict__ bf, const float* __restrict__ W1,
                              const float* __restrict__ b1, const float* __restrict__ W2,
                              const float* __restrict__ b2, float* __restrict__ slots,
                              float* __restrict__ dout){
    __shared__ float s0[8][260], pre[8][260], hb[8][260];
    const int t = threadIdx.x, b = blockIdx.x, ng = blockIdx.y;
    const int i = t >> 6, l = t & 63;
    {
        float4 v4 = *(const float4*)(slots2 + ((size_t)b*8 + i)*256 + l*4);
        float sum = v4.x + v4.y + v4.z + v4.w;
        float sq  = v4.x*v4.x + v4.y*v4.y + v4.z*v4.z + v4.w*v4.w;
        #pragma unroll
        for (int m = 1; m < 64; m <<= 1){ sum += __shfl_xor(sum, m); sq += __shfl_xor(sq, m); }
        float mean = sum * (1.f/256.f);
        float rstd = rsqrtf(sq * (1.f/256.f) - mean*mean + 1e-5f);
        float4 g4 = *(const float4*)(gf + l*4);
        float4 b4 = *(const float4*)(bf + l*4);
        s0[i][l*4+0] = v4.x; s0[i][l*4+1] = v4.y; s0[i][l*4+2] = v4.z; s0[i][l*4+3] = v4.w;
        pre[i][l*4+0] = (v4.x - mean)*rstd*g4.x + b4.x;
        pre[i][l*4+1] = (v4.y - mean)*rstd*g4.y + b4.y;
        pre[i][l*4+2] = (v4.z - mean)*rstd*g4.z + b4.z;
        pre[i][l*4+3] = (v4.w - mean)*rstd*g4.w + b4.w;
    }
    __syncthreads();
    {
        const int h4 = l*4;
        float4 acc = *(const float4*)(b1 + h4);
        #pragma unroll
        for (int cb = 0; cb < 256; cb += 16){
            float4 w4[16];
            #pragma unroll
            for (int u = 0; u < 16; ++u)
                w4[u] = *(const float4*)(W1 + (size_t)(cb+u)*256 + h4);
            #pragma unroll
            for (int u = 0; u < 16; ++u){
                float pv = pre[i][cb+u];
                acc.x += pv*w4[u].x; acc.y += pv*w4[u].y;
                acc.z += pv*w4[u].z; acc.w += pv*w4[u].w;
            }
        }
        hb[i][h4+0] = fmaxf(acc.x, 0.f); hb[i][h4+1] = fmaxf(acc.y, 0.f);
        hb[i][h4+2] = fmaxf(acc.z, 0.f); hb[i][h4+3] = fmaxf(acc.w, 0.f);
    }
    __syncthreads();
    {
        const int n = ng*64 + l;
        float acc = b2[n];
        #pragma unroll
        for (int mb = 0; mb < 256; mb += 64){
            float w[64];
            #pragma unroll
            for (int u = 0; u < 64; ++u) w[u] = W2[(size_t)(mb+u)*256 + n];
            #pragma unroll
            for (int u = 0; u < 64; ++u) acc += hb[i][mb+u]*w[u];
        }
        float val = s0[i][n] + acc;
        size_t off = ((size_t)b*8 + i)*256 + n;
        slots[off] = val;
        dout[off]  = val;
    }
}

extern "C" void kernel_launch(void* const* d_in, const int* in_sizes, int n_in,
                              void* d_out, int out_size, void* d_ws, size_t ws_size,
                              hipStream_t stream){
    const float* inputs = (const float*)d_in[0];
    const float* noise  = (const float*)d_in[1];
    const float* mu     = (const float*)d_in[2];
    const float* lsig   = (const float*)d_in[3];
    const float* g_in   = (const float*)d_in[4];
    const float* b_in   = (const float*)d_in[5];
    const float* g_s    = (const float*)d_in[6];
    const float* b_s    = (const float*)d_in[7];
    const float* g_ff   = (const float*)d_in[8];
    const float* b_ff   = (const float*)d_in[9];
    const float* Wq     = (const float*)d_in[10];
    const float* bq     = (const float*)d_in[11];
    const float* Wk     = (const float*)d_in[12];
    const float* bk     = (const float*)d_in[13];
    const float* Wv     = (const float*)d_in[14];
    const float* bv     = (const float*)d_in[15];
    const float* W_ih   = (const float*)d_in[16];
    const float* b_ih   = (const float*)d_in[17];
    const float* W_hh   = (const float*)d_in[18];
    const float* b_hh   = (const float*)d_in[19];
    const float* W1     = (const float*)d_in[20];
    const float* b1     = (const float*)d_in[21];
    const float* W2     = (const float*)d_in[22];
    const float* b2     = (const float*)d_in[23];

    char* ws = (char*)d_ws;
    unsigned short* XH  = (unsigned short*)(ws);               // 128 MB
    float* Upart        = (float*)(ws + ((size_t)128 << 20));  // 8 MB
    float* Spart        = (float*)(ws + ((size_t)136 << 20));  // 8 KB
    float* qtbuf        = (float*)(ws + ((size_t)137 << 20));  // 512 KB
    float* qbb          = (float*)(ws + ((size_t)138 << 20));  // 2 KB
    float* slots        = (float*)(ws + ((size_t)139 << 20));  // 512 KB
    float* slots2       = (float*)(ws + ((size_t)140 << 20));  // 512 KB
    float* WqkT         = (float*)(ws + ((size_t)141 << 20));  // 256 KB
    float* bqt          = (float*)(ws + ((size_t)142 << 20));  // 1 KB
    float* wqb          = (float*)(ws + ((size_t)143 << 20));  // 1 KB
    float* bqkv         = (float*)(ws + ((size_t)144 << 20));  // 4 B

    prep1_kernel<<<512, 256, 0, stream>>>(mu, lsig, noise, slots);
    prep2_kernel<<<256, 256, 0, stream>>>(Wq, Wk, bq, bk, WqkT, bqt, wqb, bqkv);
    ln_kernel<<<M_/32, 256, 0, stream>>>(inputs, g_in, b_in, XH);
    for (int it = 0; it < ITERS_; ++it){
        slotq_kernel<<<dim3(B_, 4), 512, 0, stream>>>(slots, WqkT, bqt, wqb, bqkv,
                                                      g_s, b_s, qtbuf, qbb);
        attn_kernel<<<dim3(B_, 16), 512, 0, stream>>>(XH, qtbuf, qbb, Spart, Upart);
        slotu1_kernel<<<dim3(B_, 4), 512, 0, stream>>>(slots, Spart, Upart, Wv, bv,
                                                       W_ih, b_ih, W_hh, b_hh, slots2);
        slotu2_kernel<<<dim3(B_, 4), 512, 0, stream>>>(slots2, g_ff, b_ff, W1, b1, W2, b2,
                                                       slots, (float*)d_out);
    }
}